// Round 1
// 1657.277 us; speedup vs baseline: 1.1431x; 1.1431x over previous
//
#include <hip/hip_runtime.h>
#include <cstdint>
#include <cstdio>

#define DM 1024
#define HM 4096
#define NE 7
#define NTOK 8192
#define ROWS_R 16384   // 2*NTOK routed rows
#define ROWS_T 24576   // + NTOK shared rows

typedef __bf16 bf16;
typedef __bf16 bf16x8 __attribute__((ext_vector_type(8)));
typedef __bf16 bf16x4 __attribute__((ext_vector_type(4)));
typedef float f32x4 __attribute__((ext_vector_type(4)));
typedef unsigned int u32;

__device__ __forceinline__ void gload_lds16(const bf16* g, bf16* l) {
  __builtin_amdgcn_global_load_lds((const __attribute__((address_space(1))) u32*)g,
                                   (__attribute__((address_space(3))) u32*)l, 16, 0, 0);
}

// ---------------- fp32 -> bf16 straight convert (x) ----------------
__global__ void cvt_bf16_kernel(const float* __restrict__ in, bf16* __restrict__ out, int n) {
  int i = (blockIdx.x * 256 + threadIdx.x) * 4;
  if (i >= n) return;
  float4 v = *(const float4*)(in + i);
  bf16x4 o; o[0] = (bf16)v.x; o[1] = (bf16)v.y; o[2] = (bf16)v.z; o[3] = (bf16)v.w;
  *(bf16x4*)(out + i) = o;
}

// ---------------- fp32 [R][C] -> bf16 [C][R] tiled transpose ----------------
__global__ void transpose_cvt_kernel(const float* __restrict__ in, bf16* __restrict__ out,
                                     int R, int C) {
  __shared__ float tile[32][33];
  const float* ib = in + (size_t)blockIdx.z * R * C;
  bf16* ob = out + (size_t)blockIdx.z * R * C;
  int c0 = blockIdx.x * 32, r0 = blockIdx.y * 32;
  int tx = threadIdx.x, ty = threadIdx.y;   // 32 x 8
  #pragma unroll
  for (int i = 0; i < 32; i += 8)
    tile[ty + i][tx] = ib[(size_t)(r0 + ty + i) * C + c0 + tx];
  __syncthreads();
  #pragma unroll
  for (int i = 0; i < 32; i += 8)
    ob[(size_t)(c0 + ty + i) * R + r0 + tx] = (bf16)tile[tx][ty + i];
}

// ---------------- router: logits, top-2, softmax (NO atomics) ----------------
__global__ __launch_bounds__(256) void router_kernel(
    const float* __restrict__ x, const float* __restrict__ rw,
    int* __restrict__ t_idx, float* __restrict__ t_w) {
  int wave = threadIdx.x >> 6, lane = threadIdx.x & 63;
  int t = blockIdx.x * 4 + wave;
  float acc[NE];
  #pragma unroll
  for (int e = 0; e < NE; e++) acc[e] = 0.f;
  const float* xr = x + (size_t)t * DM;
  for (int i = lane; i < DM; i += 64) {
    float xv = xr[i];
    #pragma unroll
    for (int e = 0; e < NE; e++) acc[e] += xv * rw[e * DM + i];
  }
  #pragma unroll
  for (int e = 0; e < NE; e++) {
    float v = acc[e];
    #pragma unroll
    for (int s = 32; s > 0; s >>= 1) v += __shfl_xor(v, s, 64);
    acc[e] = v;
  }
  if (lane == 0) {
    int b0 = 0; float v0 = acc[0];
    #pragma unroll
    for (int e = 1; e < NE; e++) if (acc[e] > v0) { v0 = acc[e]; b0 = e; }
    int b1 = -1; float v1 = -3.0e38f;
    #pragma unroll
    for (int e = 0; e < NE; e++) if (e != b0 && acc[e] > v1) { v1 = acc[e]; b1 = e; }
    float p0 = 1.f / (1.f + __expf(v1 - v0));  // softmax over top-2 (v0 >= v1)
    t_idx[t * 2] = b0; t_idx[t * 2 + 1] = b1;
    t_w[t * 2] = p0;  t_w[t * 2 + 1] = 1.f - p0;
  }
}

// ---------------- histogram + prefix: counts from t_idx, single block ----------------
__global__ __launch_bounds__(1024) void hist_kernel(const int* __restrict__ t_idx,
                                                    int* __restrict__ segs) {
  const int tid = threadIdx.x, wave = tid >> 6, lane = tid & 63;
  int c[NE];
  #pragma unroll
  for (int e = 0; e < NE; e++) c[e] = 0;
  for (int i = tid; i < NTOK * 2; i += 1024) {
    int e = t_idx[i];
    #pragma unroll
    for (int k = 0; k < NE; k++) c[k] += (e == k) ? 1 : 0;
  }
  __shared__ int ws[16][8];
  #pragma unroll
  for (int k = 0; k < NE; k++) {
    int v = c[k];
    #pragma unroll
    for (int s = 32; s > 0; s >>= 1) v += __shfl_xor(v, s, 64);
    if (lane == 0) ws[wave][k] = v;
  }
  __syncthreads();
  if (tid == 0) {
    int o = 0;
    for (int e = 0; e < NE; e++) {
      int cnt = 0;
      for (int w = 0; w < 16; w++) cnt += ws[w][e];
      segs[e] = o; segs[8 + e] = cnt; o += cnt;
    }
    segs[7] = ROWS_R;   // shared expert segment
    segs[15] = NTOK;
  }
}

// ---------------- fill per-expert row lists: ballot rank + 1 atomic/(block,expert) ----------------
__global__ __launch_bounds__(256) void fill_kernel(
    const int* __restrict__ t_idx, int* __restrict__ cursor,
    const int* __restrict__ segs, int* __restrict__ tok_of_row,
    int* __restrict__ row_of) {
  __shared__ int wcnt[2][4][8];   // [slot][wave][expert] counts
  __shared__ int wbase[2][4][8];  // [slot][wave][expert] intra-block offsets
  __shared__ int bbase[8];        // block base row per expert
  const int tid = threadIdx.x, wave = tid >> 6, lane = tid & 63;
  const int t = blockIdx.x * 256 + tid;
  const int e0 = t_idx[t * 2], e1 = t_idx[t * 2 + 1];
  const unsigned long long lt = (1ull << lane) - 1ull;
  int rank0 = 0, rank1 = 0;
  #pragma unroll
  for (int e = 0; e < NE; e++) {
    unsigned long long m0 = __ballot(e0 == e);
    unsigned long long m1 = __ballot(e1 == e);
    if (e0 == e) rank0 = __popcll(m0 & lt);
    if (e1 == e) rank1 = __popcll(m1 & lt);
    if (lane == 0) { wcnt[0][wave][e] = __popcll(m0); wcnt[1][wave][e] = __popcll(m1); }
  }
  __syncthreads();
  if (tid < NE) {
    int e = tid, run = 0;
    #pragma unroll
    for (int s = 0; s < 2; s++)
      #pragma unroll
      for (int w = 0; w < 4; w++) { wbase[s][w][e] = run; run += wcnt[s][w][e]; }
    bbase[e] = segs[e] + atomicAdd(&cursor[e], run);
  }
  __syncthreads();
  int r0 = bbase[e0] + wbase[0][wave][e0] + rank0;
  int r1 = bbase[e1] + wbase[1][wave][e1] + rank1;
  tok_of_row[r0] = t;  row_of[t * 2] = r0;
  tok_of_row[r1] = t;  row_of[t * 2 + 1] = r1;
  tok_of_row[ROWS_R + t] = t;  // shared segment: identity
}

// ---------------- GEMM1: h = silu(x@Wg) * (x@Wu), gathered rows ----------------
// BM=128 BN=64 BK=32; 4 waves, each 64rows x 32cols per matrix; two B matrices fused.
// e_fixed >= 0: expert index fixed (gridDim.z == 1). compact: weight base has no
// per-expert stride and hb is indexed from row 0 (per-expert slot reuse).
__global__ __launch_bounds__(256, 2) void gemm1_kernel(
    const bf16* __restrict__ xb, const bf16* __restrict__ wgT, const bf16* __restrict__ wuT,
    const bf16* __restrict__ swgT, const bf16* __restrict__ swuT,
    const int* __restrict__ segs, const int* __restrict__ tok_of_row,
    bf16* __restrict__ hb, int e_fixed, int compact) {
  const int e = (e_fixed >= 0) ? e_fixed : (int)blockIdx.z;
  const int off = segs[e], cnt = segs[8 + e];
  const int hoff = compact ? 0 : off;
  const int r0 = blockIdx.y * 128;
  if (r0 >= cnt) return;
  const int n0 = blockIdx.x * 64;
  const size_t estride = compact ? 0 : (size_t)e * HM * DM;
  const bf16* bg = (e < NE) ? wgT + estride : swgT;
  const bf16* bu = (e < NE) ? wuT + estride : swuT;

  __shared__ __align__(16) bf16 As[128 * 32];
  __shared__ __align__(16) bf16 Bgs[64 * 32];
  __shared__ __align__(16) bf16 Bus[64 * 32];

  const int tid = threadIdx.x, wave = tid >> 6, lane = tid & 63;
  int lr0 = wave * 16 + (lane >> 2);
  int lr1 = lr0 + 64;
  int i0 = min(r0 + lr0, cnt - 1);
  int i1 = min(r0 + lr1, cnt - 1);
  const bf16* agp0 = xb + (size_t)tok_of_row[off + i0] * DM + (lane & 3) * 8;
  const bf16* agp1 = xb + (size_t)tok_of_row[off + i1] * DM + (lane & 3) * 8;
  const bf16* bgp = bg + (size_t)(n0 + lr0) * DM + (lane & 3) * 8;
  const bf16* bup = bu + (size_t)(n0 + lr0) * DM + (lane & 3) * 8;
  bf16* As_w0 = &As[wave * 512];
  bf16* As_w1 = &As[(4 + wave) * 512];
  bf16* Bgs_w = &Bgs[wave * 512];
  bf16* Bus_w = &Bus[wave * 512];

  const int wr = wave & 1, wc = wave >> 1;
  const int mbase = wr * 64, nbase = wc * 32;
  const int fl = lane & 15, fq = lane >> 4;
  f32x4 accg[4][2] = {}; f32x4 accu[4][2] = {};

  for (int k0 = 0; k0 < DM; k0 += 32) {
    gload_lds16(agp0 + k0, As_w0);
    gload_lds16(agp1 + k0, As_w1);
    gload_lds16(bgp + k0, Bgs_w);
    gload_lds16(bup + k0, Bus_w);
    __syncthreads();
    bf16x8 af[4], bgf[2], buf[2];
    #pragma unroll
    for (int i = 0; i < 4; i++)
      af[i] = *(const bf16x8*)&As[(mbase + i * 16 + fl) * 32 + fq * 8];
    #pragma unroll
    for (int j = 0; j < 2; j++) {
      bgf[j] = *(const bf16x8*)&Bgs[(nbase + j * 16 + fl) * 32 + fq * 8];
      buf[j] = *(const bf16x8*)&Bus[(nbase + j * 16 + fl) * 32 + fq * 8];
    }
    #pragma unroll
    for (int i = 0; i < 4; i++)
      #pragma unroll
      for (int j = 0; j < 2; j++) {
        accg[i][j] = __builtin_amdgcn_mfma_f32_16x16x32_bf16(af[i], bgf[j], accg[i][j], 0, 0, 0);
        accu[i][j] = __builtin_amdgcn_mfma_f32_16x16x32_bf16(af[i], buf[j], accu[i][j], 0, 0, 0);
      }
    __syncthreads();
  }
  #pragma unroll
  for (int i = 0; i < 4; i++)
    #pragma unroll
    for (int j = 0; j < 2; j++)
      #pragma unroll
      for (int r = 0; r < 4; r++) {
        int lr = mbase + i * 16 + fq * 4 + r;
        if (r0 + lr < cnt) {
          float g = accg[i][j][r], u = accu[i][j][r];
          float s = g / (1.f + __expf(-g));
          int col = n0 + nbase + j * 16 + fl;
          hb[(size_t)(hoff + r0 + lr) * HM + col] = (bf16)(s * u);
        }
      }
}

// ---------------- GEMM2: y = h @ Wd, compact rows ----------------
// BM=128 BN=128 BK=32; 4 waves each 64x64.
__global__ __launch_bounds__(256, 2) void gemm2_kernel(
    const bf16* __restrict__ hb, const bf16* __restrict__ wdT, const bf16* __restrict__ swdT,
    const int* __restrict__ segs, bf16* __restrict__ yb, int e_fixed, int compact) {
  const int e = (e_fixed >= 0) ? e_fixed : (int)blockIdx.z;
  const int off = segs[e], cnt = segs[8 + e];
  const int hoff = compact ? 0 : off;
  const int r0 = blockIdx.y * 128;
  if (r0 >= cnt) return;
  const int n0 = blockIdx.x * 128;
  const size_t estride = compact ? 0 : (size_t)e * DM * HM;
  const bf16* bd = (e < NE) ? wdT + estride : swdT;

  __shared__ __align__(16) bf16 As[128 * 32];
  __shared__ __align__(16) bf16 Bs[128 * 32];

  const int tid = threadIdx.x, wave = tid >> 6, lane = tid & 63;
  int lr0 = wave * 16 + (lane >> 2);
  int lr1 = lr0 + 64;
  int i0 = min(r0 + lr0, cnt - 1);
  int i1 = min(r0 + lr1, cnt - 1);
  const bf16* agp0 = hb + (size_t)(hoff + i0) * HM + (lane & 3) * 8;
  const bf16* agp1 = hb + (size_t)(hoff + i1) * HM + (lane & 3) * 8;
  const bf16* bgp0 = bd + (size_t)(n0 + lr0) * HM + (lane & 3) * 8;
  const bf16* bgp1 = bgp0 + (size_t)64 * HM;
  bf16* As_w0 = &As[wave * 512];
  bf16* As_w1 = &As[(4 + wave) * 512];
  bf16* Bs_w0 = &Bs[wave * 512];
  bf16* Bs_w1 = &Bs[(4 + wave) * 512];

  const int wr = wave & 1, wc = wave >> 1;
  const int mbase = wr * 64, nbase = wc * 64;
  const int fl = lane & 15, fq = lane >> 4;
  f32x4 acc[4][4] = {};

  for (int k0 = 0; k0 < HM; k0 += 32) {
    gload_lds16(agp0 + k0, As_w0);
    gload_lds16(agp1 + k0, As_w1);
    gload_lds16(bgp0 + k0, Bs_w0);
    gload_lds16(bgp1 + k0, Bs_w1);
    __syncthreads();
    bf16x8 af[4], bf[4];
    #pragma unroll
    for (int i = 0; i < 4; i++) {
      af[i] = *(const bf16x8*)&As[(mbase + i * 16 + fl) * 32 + fq * 8];
      bf[i] = *(const bf16x8*)&Bs[(nbase + i * 16 + fl) * 32 + fq * 8];
    }
    #pragma unroll
    for (int i = 0; i < 4; i++)
      #pragma unroll
      for (int j = 0; j < 4; j++)
        acc[i][j] = __builtin_amdgcn_mfma_f32_16x16x32_bf16(af[i], bf[j], acc[i][j], 0, 0, 0);
    __syncthreads();
  }
  #pragma unroll
  for (int i = 0; i < 4; i++)
    #pragma unroll
    for (int j = 0; j < 4; j++)
      #pragma unroll
      for (int r = 0; r < 4; r++) {
        int lr = mbase + i * 16 + fq * 4 + r;
        if (r0 + lr < cnt) {
          int col = n0 + nbase + j * 16 + fl;
          yb[(size_t)(off + r0 + lr) * DM + col] = (bf16)acc[i][j][r];
        }
      }
}

// ---------------- combine: out = w0*y[r0] + w1*y[r1] + y[shared] ----------------
__global__ __launch_bounds__(256) void combine_kernel(
    const bf16* __restrict__ yb, const int* __restrict__ row_of,
    const float* __restrict__ t_w, float* __restrict__ out) {
  int t = blockIdx.x;
  int d = threadIdx.x * 4;
  int r0 = row_of[t * 2], r1 = row_of[t * 2 + 1];
  float w0 = t_w[t * 2], w1 = t_w[t * 2 + 1];
  bf16x4 a = *(const bf16x4*)&yb[(size_t)r0 * DM + d];
  bf16x4 b = *(const bf16x4*)&yb[(size_t)r1 * DM + d];
  bf16x4 c = *(const bf16x4*)&yb[(size_t)(ROWS_R + t) * DM + d];
  float4 o;
  o.x = w0 * (float)a[0] + w1 * (float)b[0] + (float)c[0];
  o.y = w0 * (float)a[1] + w1 * (float)b[1] + (float)c[1];
  o.z = w0 * (float)a[2] + w1 * (float)b[2] + (float)c[2];
  o.w = w0 * (float)a[3] + w1 * (float)b[3] + (float)c[3];
  *(float4*)&out[(size_t)t * DM + d] = o;
}

extern "C" void kernel_launch(void* const* d_in, const int* in_sizes, int n_in,
                              void* d_out, int out_size, void* d_ws, size_t ws_size,
                              hipStream_t stream) {
  const float* x        = (const float*)d_in[0];
  const float* router_w = (const float*)d_in[1];
  const float* w_gate   = (const float*)d_in[2];
  const float* w_up     = (const float*)d_in[3];
  const float* w_down   = (const float*)d_in[4];
  const float* sw_gate  = (const float*)d_in[5];
  const float* sw_up    = (const float*)d_in[6];
  const float* sw_down  = (const float*)d_in[7];
  float* out = (float*)d_out;

  const size_t WEXP = (size_t)HM * DM;           // elements per expert weight matrix
  // tier-1 needs ~470 MB; tier-2 needs ~160 MB
  const size_t NEED_T1 = (size_t)NTOK * DM * 2 + 7 * WEXP * 2 * 3 + 3 * WEXP * 2 +
                         (size_t)ROWS_T * HM * 2 + (size_t)ROWS_T * DM * 2 + (1 << 20);
  const bool tier1 = ws_size >= NEED_T1 + (16 << 20);

  char* p = (char*)d_ws;
  auto alloc = [&](size_t bytes) { char* r = p; p += (bytes + 255) & ~(size_t)255; return r; };

  bf16* xb = (bf16*)alloc((size_t)NTOK * DM * 2);
  bf16 *wgT, *wuT, *wdT, *swgT, *swuT, *swdT, *hb, *yb;
  if (tier1) {
    wgT  = (bf16*)alloc(7 * WEXP * 2);
    wuT  = (bf16*)alloc(7 * WEXP * 2);
    wdT  = (bf16*)alloc(7 * WEXP * 2);
    swgT = (bf16*)alloc(WEXP * 2);
    swuT = (bf16*)alloc(WEXP * 2);
    swdT = (bf16*)alloc(WEXP * 2);
    hb   = (bf16*)alloc((size_t)ROWS_T * HM * 2);   // full: all experts + shared
  } else {
    wgT  = (bf16*)alloc(WEXP * 2);   // single-expert slots, reused
    wuT  = (bf16*)alloc(WEXP * 2);
    wdT  = (bf16*)alloc(WEXP * 2);
    swgT = wgT; swuT = wuT; swdT = wdT;
    hb   = (bf16*)alloc((size_t)NTOK * HM * 2);     // one expert (worst case all tokens)
  }
  yb = (bf16*)alloc((size_t)ROWS_T * DM * 2);
  int* cursor     = (int*)alloc(8 * 4);
  int* segs       = (int*)alloc(16 * 4);
  int* t_idx      = (int*)alloc((size_t)NTOK * 2 * 4);
  int* row_of     = (int*)alloc((size_t)NTOK * 2 * 4);
  int* tok_of_row = (int*)alloc((size_t)ROWS_T * 4);
  float* t_w      = (float*)alloc((size_t)NTOK * 2 * 4);
  if ((size_t)(p - (char*)d_ws) > ws_size) {
    fprintf(stderr, "MoE kernel: ws too small: need %zu have %zu (tier1=%d)\n",
            (size_t)(p - (char*)d_ws), ws_size, (int)tier1);
    return;  // refuse to launch OOB — fails validation instead of crashing
  }

  hipMemsetAsync(cursor, 0, 8 * 4, stream);

  cvt_bf16_kernel<<<(NTOK * DM) / 1024, 256, 0, stream>>>(x, xb, NTOK * DM);
  router_kernel<<<NTOK / 4, 256, 0, stream>>>(x, router_w, t_idx, t_w);
  hist_kernel<<<1, 1024, 0, stream>>>(t_idx, segs);
  fill_kernel<<<NTOK / 256, 256, 0, stream>>>(t_idx, cursor, segs, tok_of_row, row_of);

  const dim3 tb(32, 8);
  const dim3 tg_gu(HM / 32, DM / 32, 1);   // gate/up: [DM][HM] -> [HM][DM]
  const dim3 tg_d(DM / 32, HM / 32, 1);    // down:    [HM][DM] -> [DM][HM]

  if (tier1) {
    transpose_cvt_kernel<<<dim3(HM / 32, DM / 32, NE), tb, 0, stream>>>(w_gate, wgT, DM, HM);
    transpose_cvt_kernel<<<dim3(HM / 32, DM / 32, NE), tb, 0, stream>>>(w_up, wuT, DM, HM);
    transpose_cvt_kernel<<<dim3(DM / 32, HM / 32, NE), tb, 0, stream>>>(w_down, wdT, HM, DM);
    transpose_cvt_kernel<<<tg_gu, tb, 0, stream>>>(sw_gate, swgT, DM, HM);
    transpose_cvt_kernel<<<tg_gu, tb, 0, stream>>>(sw_up, swuT, DM, HM);
    transpose_cvt_kernel<<<tg_d, tb, 0, stream>>>(sw_down, swdT, HM, DM);
    gemm1_kernel<<<dim3(HM / 64, 64, 8), 256, 0, stream>>>(
        xb, wgT, wuT, swgT, swuT, segs, tok_of_row, hb, -1, 0);
    gemm2_kernel<<<dim3(DM / 128, 64, 8), 256, 0, stream>>>(
        hb, wdT, swdT, segs, yb, -1, 0);
  } else {
    // shared expert first (uses the weight slots), then routed experts reuse slots + hb
    transpose_cvt_kernel<<<tg_gu, tb, 0, stream>>>(sw_gate, swgT, DM, HM);
    transpose_cvt_kernel<<<tg_gu, tb, 0, stream>>>(sw_up, swuT, DM, HM);
    transpose_cvt_kernel<<<tg_d, tb, 0, stream>>>(sw_down, swdT, HM, DM);
    gemm1_kernel<<<dim3(HM / 64, 64, 1), 256, 0, stream>>>(
        xb, wgT, wuT, swgT, swuT, segs, tok_of_row, hb, 7, 1);
    gemm2_kernel<<<dim3(DM / 128, 64, 1), 256, 0, stream>>>(
        hb, wdT, swdT, segs, yb, 7, 1);
    for (int e = 0; e < NE; e++) {
      transpose_cvt_kernel<<<tg_gu, tb, 0, stream>>>(w_gate + (size_t)e * WEXP, wgT, DM, HM);
      transpose_cvt_kernel<<<tg_gu, tb, 0, stream>>>(w_up + (size_t)e * WEXP, wuT, DM, HM);
      transpose_cvt_kernel<<<tg_d, tb, 0, stream>>>(w_down + (size_t)e * WEXP, wdT, HM, DM);
      gemm1_kernel<<<dim3(HM / 64, 64, 1), 256, 0, stream>>>(
          xb, wgT, wuT, swgT, swuT, segs, tok_of_row, hb, e, 1);
      gemm2_kernel<<<dim3(DM / 128, 64, 1), 256, 0, stream>>>(
          hb, wdT, swdT, segs, yb, e, 1);
    }
  }
  combine_kernel<<<NTOK, 256, 0, stream>>>(yb, row_of, t_w, out);
}

// Round 2
// 1414.414 us; speedup vs baseline: 1.3394x; 1.1717x over previous
//
#include <hip/hip_runtime.h>
#include <cstdint>
#include <cstdio>

#define DM 1024
#define HM 4096
#define NE 7
#define NTOK 8192
#define ROWS_R 16384   // 2*NTOK routed rows
#define ROWS_T 24576   // + NTOK shared rows
#define WEXP_ELEMS ((size_t)HM * DM)

typedef __bf16 bf16;
typedef __bf16 bf16x8 __attribute__((ext_vector_type(8)));
typedef __bf16 bf16x4 __attribute__((ext_vector_type(4)));
typedef float f32x4 __attribute__((ext_vector_type(4)));
typedef unsigned int u32;

__device__ __forceinline__ void gload_lds16(const bf16* g, bf16* l) {
  __builtin_amdgcn_global_load_lds((const __attribute__((address_space(1))) u32*)g,
                                   (__attribute__((address_space(3))) u32*)l, 16, 0, 0);
}

// ---------------- fp32 -> bf16 straight convert (x) ----------------
__global__ void cvt_bf16_kernel(const float* __restrict__ in, bf16* __restrict__ out, int n) {
  int i = (blockIdx.x * 256 + threadIdx.x) * 4;
  if (i >= n) return;
  float4 v = *(const float4*)(in + i);
  bf16x4 o; o[0] = (bf16)v.x; o[1] = (bf16)v.y; o[2] = (bf16)v.z; o[3] = (bf16)v.w;
  *(bf16x4*)(out + i) = o;
}

// ---------------- shared transpose tile body ----------------
__device__ __forceinline__ void transpose_tile(const float* __restrict__ ib,
                                               bf16* __restrict__ ob,
                                               int R, int C, int bx, int by,
                                               int tx, int ty) {
  __shared__ float tile[32][33];
  int c0 = bx * 32, r0 = by * 32;
  #pragma unroll
  for (int i = 0; i < 32; i += 8)
    tile[ty + i][tx] = ib[(size_t)(r0 + ty + i) * C + c0 + tx];
  __syncthreads();
  #pragma unroll
  for (int i = 0; i < 32; i += 8)
    ob[(size_t)(c0 + ty + i) * R + r0 + tx] = (bf16)tile[tx][ty + i];
}

// ---------------- fp32 [R][C] -> bf16 [C][R], z strides through experts ----------------
__global__ void transpose_cvt_kernel(const float* __restrict__ in, bf16* __restrict__ out,
                                     int R, int C) {
  const float* ib = in + (size_t)blockIdx.z * R * C;
  bf16* ob = out + (size_t)blockIdx.z * R * C;
  transpose_tile(ib, ob, R, C, blockIdx.x, blockIdx.y, threadIdx.x, threadIdx.y);
}

// ---------------- pair transpose: z=0 -> (s0,d0), z=1 -> (s1,d1), same R,C ----------------
__global__ void transpose_cvt_pair(const float* __restrict__ s0, const float* __restrict__ s1,
                                   bf16* __restrict__ d0, bf16* __restrict__ d1,
                                   int R, int C) {
  const float* ib = blockIdx.z ? s1 : s0;
  bf16* ob = blockIdx.z ? d1 : d0;
  transpose_tile(ib, ob, R, C, blockIdx.x, blockIdx.y, threadIdx.x, threadIdx.y);
}

// ---------------- w_down batch transpose: z<7 routed expert z, z==7 shared ----------------
__global__ void transpose_cvt_wd(const float* __restrict__ wd, const float* __restrict__ swd,
                                 bf16* __restrict__ wdT, bf16* __restrict__ swdT) {
  int z = blockIdx.z;
  const float* ib = (z < NE) ? wd + (size_t)z * WEXP_ELEMS : swd;
  bf16* ob = (z < NE) ? wdT + (size_t)z * WEXP_ELEMS : swdT;
  transpose_tile(ib, ob, HM, DM, blockIdx.x, blockIdx.y, threadIdx.x, threadIdx.y);
}

// ---------------- triple transpose (tier-2): z=0 gate, z=1 up (DMxHM), z=2 down (HMxDM) ----
__global__ void transpose_cvt3(const float* __restrict__ g, const float* __restrict__ u,
                               const float* __restrict__ d,
                               bf16* __restrict__ og, bf16* __restrict__ ou,
                               bf16* __restrict__ od) {
  int z = blockIdx.z;
  int R = (z == 2) ? HM : DM, C = (z == 2) ? DM : HM;
  int nbx = C / 32;
  int bid = blockIdx.x;
  int bx = bid % nbx, by = bid / nbx;
  const float* ib = (z == 0) ? g : ((z == 1) ? u : d);
  bf16* ob = (z == 0) ? og : ((z == 1) ? ou : od);
  transpose_tile(ib, ob, R, C, bx, by, threadIdx.x, threadIdx.y);
}

// ---------------- router: logits, top-2, softmax (NO atomics) ----------------
__global__ __launch_bounds__(256) void router_kernel(
    const float* __restrict__ x, const float* __restrict__ rw,
    int* __restrict__ t_idx, float* __restrict__ t_w) {
  int wave = threadIdx.x >> 6, lane = threadIdx.x & 63;
  int t = blockIdx.x * 4 + wave;
  float acc[NE];
  #pragma unroll
  for (int e = 0; e < NE; e++) acc[e] = 0.f;
  const float* xr = x + (size_t)t * DM;
  for (int i = lane; i < DM; i += 64) {
    float xv = xr[i];
    #pragma unroll
    for (int e = 0; e < NE; e++) acc[e] += xv * rw[e * DM + i];
  }
  #pragma unroll
  for (int e = 0; e < NE; e++) {
    float v = acc[e];
    #pragma unroll
    for (int s = 32; s > 0; s >>= 1) v += __shfl_xor(v, s, 64);
    acc[e] = v;
  }
  if (lane == 0) {
    int b0 = 0; float v0 = acc[0];
    #pragma unroll
    for (int e = 1; e < NE; e++) if (acc[e] > v0) { v0 = acc[e]; b0 = e; }
    int b1 = -1; float v1 = -3.0e38f;
    #pragma unroll
    for (int e = 0; e < NE; e++) if (e != b0 && acc[e] > v1) { v1 = acc[e]; b1 = e; }
    float p0 = 1.f / (1.f + __expf(v1 - v0));  // softmax over top-2 (v0 >= v1)
    t_idx[t * 2] = b0; t_idx[t * 2 + 1] = b1;
    t_w[t * 2] = p0;  t_w[t * 2 + 1] = 1.f - p0;
  }
}

// ---------------- histogram + prefix: counts from t_idx, single block ----------------
__global__ __launch_bounds__(1024) void hist_kernel(const int* __restrict__ t_idx,
                                                    int* __restrict__ segs) {
  const int tid = threadIdx.x, wave = tid >> 6, lane = tid & 63;
  int c[NE];
  #pragma unroll
  for (int e = 0; e < NE; e++) c[e] = 0;
  for (int i = tid; i < NTOK * 2; i += 1024) {
    int e = t_idx[i];
    #pragma unroll
    for (int k = 0; k < NE; k++) c[k] += (e == k) ? 1 : 0;
  }
  __shared__ int ws[16][8];
  #pragma unroll
  for (int k = 0; k < NE; k++) {
    int v = c[k];
    #pragma unroll
    for (int s = 32; s > 0; s >>= 1) v += __shfl_xor(v, s, 64);
    if (lane == 0) ws[wave][k] = v;
  }
  __syncthreads();
  if (tid == 0) {
    int o = 0;
    for (int e = 0; e < NE; e++) {
      int cnt = 0;
      for (int w = 0; w < 16; w++) cnt += ws[w][e];
      segs[e] = o; segs[8 + e] = cnt; o += cnt;
    }
    segs[7] = ROWS_R;   // shared expert segment
    segs[15] = NTOK;
  }
}

// ---------------- fill per-expert row lists: ballot rank + 1 atomic/(block,expert) ----------------
__global__ __launch_bounds__(256) void fill_kernel(
    const int* __restrict__ t_idx, int* __restrict__ cursor,
    const int* __restrict__ segs, int* __restrict__ tok_of_row,
    int* __restrict__ row_of) {
  __shared__ int wcnt[2][4][8];   // [slot][wave][expert] counts
  __shared__ int wbase[2][4][8];  // [slot][wave][expert] intra-block offsets
  __shared__ int bbase[8];        // block base row per expert
  const int tid = threadIdx.x, wave = tid >> 6, lane = tid & 63;
  const int t = blockIdx.x * 256 + tid;
  const int e0 = t_idx[t * 2], e1 = t_idx[t * 2 + 1];
  const unsigned long long lt = (1ull << lane) - 1ull;
  int rank0 = 0, rank1 = 0;
  #pragma unroll
  for (int e = 0; e < NE; e++) {
    unsigned long long m0 = __ballot(e0 == e);
    unsigned long long m1 = __ballot(e1 == e);
    if (e0 == e) rank0 = __popcll(m0 & lt);
    if (e1 == e) rank1 = __popcll(m1 & lt);
    if (lane == 0) { wcnt[0][wave][e] = __popcll(m0); wcnt[1][wave][e] = __popcll(m1); }
  }
  __syncthreads();
  if (tid < NE) {
    int e = tid, run = 0;
    #pragma unroll
    for (int s = 0; s < 2; s++)
      #pragma unroll
      for (int w = 0; w < 4; w++) { wbase[s][w][e] = run; run += wcnt[s][w][e]; }
    bbase[e] = segs[e] + atomicAdd(&cursor[e], run);
  }
  __syncthreads();
  int r0 = bbase[e0] + wbase[0][wave][e0] + rank0;
  int r1 = bbase[e1] + wbase[1][wave][e1] + rank1;
  tok_of_row[r0] = t;  row_of[t * 2] = r0;
  tok_of_row[r1] = t;  row_of[t * 2 + 1] = r1;
  tok_of_row[ROWS_R + t] = t;  // shared segment: identity
}

// ---------------- GEMM1: h = silu(x@Wg) * (x@Wu), gathered rows ----------------
// BM=128 BN=64 BK=32; 4 waves, each 64rows x 32cols per matrix; two B matrices fused.
// e_fixed >= 0: expert index fixed (gridDim.z == 1).
// wcompact: weight base has no per-expert stride (single-expert slot reuse).
// hcompact: hb indexed from row 0 instead of segment offset.
__global__ __launch_bounds__(256, 2) void gemm1_kernel(
    const bf16* __restrict__ xb, const bf16* __restrict__ wgT, const bf16* __restrict__ wuT,
    const bf16* __restrict__ swgT, const bf16* __restrict__ swuT,
    const int* __restrict__ segs, const int* __restrict__ tok_of_row,
    bf16* __restrict__ hb, int e_fixed, int wcompact, int hcompact) {
  const int e = (e_fixed >= 0) ? e_fixed : (int)blockIdx.z;
  const int off = segs[e], cnt = segs[8 + e];
  const int hoff = hcompact ? 0 : off;
  const int r0 = blockIdx.y * 128;
  if (r0 >= cnt) return;
  const int n0 = blockIdx.x * 64;
  const size_t estride = wcompact ? 0 : (size_t)e * WEXP_ELEMS;
  const bf16* bg = (e < NE) ? wgT + estride : swgT;
  const bf16* bu = (e < NE) ? wuT + estride : swuT;

  __shared__ __align__(16) bf16 As[128 * 32];
  __shared__ __align__(16) bf16 Bgs[64 * 32];
  __shared__ __align__(16) bf16 Bus[64 * 32];

  const int tid = threadIdx.x, wave = tid >> 6, lane = tid & 63;
  int lr0 = wave * 16 + (lane >> 2);
  int lr1 = lr0 + 64;
  int i0 = min(r0 + lr0, cnt - 1);
  int i1 = min(r0 + lr1, cnt - 1);
  const bf16* agp0 = xb + (size_t)tok_of_row[off + i0] * DM + (lane & 3) * 8;
  const bf16* agp1 = xb + (size_t)tok_of_row[off + i1] * DM + (lane & 3) * 8;
  const bf16* bgp = bg + (size_t)(n0 + lr0) * DM + (lane & 3) * 8;
  const bf16* bup = bu + (size_t)(n0 + lr0) * DM + (lane & 3) * 8;
  bf16* As_w0 = &As[wave * 512];
  bf16* As_w1 = &As[(4 + wave) * 512];
  bf16* Bgs_w = &Bgs[wave * 512];
  bf16* Bus_w = &Bus[wave * 512];

  const int wr = wave & 1, wc = wave >> 1;
  const int mbase = wr * 64, nbase = wc * 32;
  const int fl = lane & 15, fq = lane >> 4;
  f32x4 accg[4][2] = {}; f32x4 accu[4][2] = {};

  for (int k0 = 0; k0 < DM; k0 += 32) {
    gload_lds16(agp0 + k0, As_w0);
    gload_lds16(agp1 + k0, As_w1);
    gload_lds16(bgp + k0, Bgs_w);
    gload_lds16(bup + k0, Bus_w);
    __syncthreads();
    bf16x8 af[4], bgf[2], buf[2];
    #pragma unroll
    for (int i = 0; i < 4; i++)
      af[i] = *(const bf16x8*)&As[(mbase + i * 16 + fl) * 32 + fq * 8];
    #pragma unroll
    for (int j = 0; j < 2; j++) {
      bgf[j] = *(const bf16x8*)&Bgs[(nbase + j * 16 + fl) * 32 + fq * 8];
      buf[j] = *(const bf16x8*)&Bus[(nbase + j * 16 + fl) * 32 + fq * 8];
    }
    #pragma unroll
    for (int i = 0; i < 4; i++)
      #pragma unroll
      for (int j = 0; j < 2; j++) {
        accg[i][j] = __builtin_amdgcn_mfma_f32_16x16x32_bf16(af[i], bgf[j], accg[i][j], 0, 0, 0);
        accu[i][j] = __builtin_amdgcn_mfma_f32_16x16x32_bf16(af[i], buf[j], accu[i][j], 0, 0, 0);
      }
    __syncthreads();
  }
  #pragma unroll
  for (int i = 0; i < 4; i++)
    #pragma unroll
    for (int j = 0; j < 2; j++)
      #pragma unroll
      for (int r = 0; r < 4; r++) {
        int lr = mbase + i * 16 + fq * 4 + r;
        if (r0 + lr < cnt) {
          float g = accg[i][j][r], u = accu[i][j][r];
          float s = g / (1.f + __expf(-g));
          int col = n0 + nbase + j * 16 + fl;
          hb[(size_t)(hoff + r0 + lr) * HM + col] = (bf16)(s * u);
        }
      }
}

// ---------------- GEMM2: y = h @ Wd ----------------
// BM=128 BN=128 BK=32; 4 waves each 64x64.
__global__ __launch_bounds__(256, 2) void gemm2_kernel(
    const bf16* __restrict__ hb, const bf16* __restrict__ wdT, const bf16* __restrict__ swdT,
    const int* __restrict__ segs, bf16* __restrict__ yb, int e_fixed, int wcompact,
    int hcompact) {
  const int e = (e_fixed >= 0) ? e_fixed : (int)blockIdx.z;
  const int off = segs[e], cnt = segs[8 + e];
  const int hoff = hcompact ? 0 : off;
  const int r0 = blockIdx.y * 128;
  if (r0 >= cnt) return;
  const int n0 = blockIdx.x * 128;
  const size_t estride = wcompact ? 0 : (size_t)e * WEXP_ELEMS;
  const bf16* bd = (e < NE) ? wdT + estride : swdT;

  __shared__ __align__(16) bf16 As[128 * 32];
  __shared__ __align__(16) bf16 Bs[128 * 32];

  const int tid = threadIdx.x, wave = tid >> 6, lane = tid & 63;
  int lr0 = wave * 16 + (lane >> 2);
  int lr1 = lr0 + 64;
  int i0 = min(r0 + lr0, cnt - 1);
  int i1 = min(r0 + lr1, cnt - 1);
  const bf16* agp0 = hb + (size_t)(hoff + i0) * HM + (lane & 3) * 8;
  const bf16* agp1 = hb + (size_t)(hoff + i1) * HM + (lane & 3) * 8;
  const bf16* bgp0 = bd + (size_t)(n0 + lr0) * HM + (lane & 3) * 8;
  const bf16* bgp1 = bgp0 + (size_t)64 * HM;
  bf16* As_w0 = &As[wave * 512];
  bf16* As_w1 = &As[(4 + wave) * 512];
  bf16* Bs_w0 = &Bs[wave * 512];
  bf16* Bs_w1 = &Bs[(4 + wave) * 512];

  const int wr = wave & 1, wc = wave >> 1;
  const int mbase = wr * 64, nbase = wc * 64;
  const int fl = lane & 15, fq = lane >> 4;
  f32x4 acc[4][4] = {};

  for (int k0 = 0; k0 < HM; k0 += 32) {
    gload_lds16(agp0 + k0, As_w0);
    gload_lds16(agp1 + k0, As_w1);
    gload_lds16(bgp0 + k0, Bs_w0);
    gload_lds16(bgp1 + k0, Bs_w1);
    __syncthreads();
    bf16x8 af[4], bf[4];
    #pragma unroll
    for (int i = 0; i < 4; i++) {
      af[i] = *(const bf16x8*)&As[(mbase + i * 16 + fl) * 32 + fq * 8];
      bf[i] = *(const bf16x8*)&Bs[(nbase + i * 16 + fl) * 32 + fq * 8];
    }
    #pragma unroll
    for (int i = 0; i < 4; i++)
      #pragma unroll
      for (int j = 0; j < 4; j++)
        acc[i][j] = __builtin_amdgcn_mfma_f32_16x16x32_bf16(af[i], bf[j], acc[i][j], 0, 0, 0);
    __syncthreads();
  }
  #pragma unroll
  for (int i = 0; i < 4; i++)
    #pragma unroll
    for (int j = 0; j < 4; j++)
      #pragma unroll
      for (int r = 0; r < 4; r++) {
        int lr = mbase + i * 16 + fq * 4 + r;
        if (r0 + lr < cnt) {
          int col = n0 + nbase + j * 16 + fl;
          yb[(size_t)(off + r0 + lr) * DM + col] = (bf16)acc[i][j][r];
        }
      }
}

// ---------------- combine: out = w0*y[r0] + w1*y[r1] + y[shared] ----------------
__global__ __launch_bounds__(256) void combine_kernel(
    const bf16* __restrict__ yb, const int* __restrict__ row_of,
    const float* __restrict__ t_w, float* __restrict__ out) {
  int t = blockIdx.x;
  int d = threadIdx.x * 4;
  int r0 = row_of[t * 2], r1 = row_of[t * 2 + 1];
  float w0 = t_w[t * 2], w1 = t_w[t * 2 + 1];
  bf16x4 a = *(const bf16x4*)&yb[(size_t)r0 * DM + d];
  bf16x4 b = *(const bf16x4*)&yb[(size_t)r1 * DM + d];
  bf16x4 c = *(const bf16x4*)&yb[(size_t)(ROWS_R + t) * DM + d];
  float4 o;
  o.x = w0 * (float)a[0] + w1 * (float)b[0] + (float)c[0];
  o.y = w0 * (float)a[1] + w1 * (float)b[1] + (float)c[1];
  o.z = w0 * (float)a[2] + w1 * (float)b[2] + (float)c[2];
  o.w = w0 * (float)a[3] + w1 * (float)b[3] + (float)c[3];
  *(float4*)&out[(size_t)t * DM + d] = o;
}

extern "C" void kernel_launch(void* const* d_in, const int* in_sizes, int n_in,
                              void* d_out, int out_size, void* d_ws, size_t ws_size,
                              hipStream_t stream) {
  const float* x        = (const float*)d_in[0];
  const float* router_w = (const float*)d_in[1];
  const float* w_gate   = (const float*)d_in[2];
  const float* w_up     = (const float*)d_in[3];
  const float* w_down   = (const float*)d_in[4];
  const float* sw_gate  = (const float*)d_in[5];
  const float* sw_up    = (const float*)d_in[6];
  const float* sw_down  = (const float*)d_in[7];
  float* out = (float*)d_out;

  const size_t WB = WEXP_ELEMS * 2;              // bytes per expert weight matrix (bf16)
  const size_t MISC = (size_t)2 << 20;
  const size_t NEED_T1  = (size_t)NTOK * DM * 2 + 21 * WB + 3 * WB +
                          (size_t)ROWS_T * HM * 2 + (size_t)ROWS_T * DM * 2 + MISC;
  const size_t NEED_T15 = (size_t)NTOK * DM * 2 + 2 * WB + 7 * WB + WB +
                          (size_t)ROWS_R * HM * 2 + (size_t)ROWS_T * DM * 2 + MISC;
  const size_t NEED_T2  = (size_t)NTOK * DM * 2 + 3 * WB +
                          (size_t)NTOK * HM * 2 + (size_t)ROWS_T * DM * 2 + MISC;
  const int tier = (ws_size >= NEED_T1 + (16 << 20)) ? 1
                 : (ws_size >= NEED_T15 + (8 << 20)) ? 2 : 3;  // 2 == tier-1.5

  char* p = (char*)d_ws;
  auto alloc = [&](size_t bytes) { char* r = p; p += (bytes + 255) & ~(size_t)255; return r; };

  bf16* xb = (bf16*)alloc((size_t)NTOK * DM * 2);
  bf16 *wgT, *wuT, *wdT, *swgT, *swuT, *swdT, *hb, *yb;
  if (tier == 1) {
    wgT  = (bf16*)alloc(7 * WB);
    wuT  = (bf16*)alloc(7 * WB);
    wdT  = (bf16*)alloc(7 * WB);
    swgT = (bf16*)alloc(WB);
    swuT = (bf16*)alloc(WB);
    swdT = (bf16*)alloc(WB);
    hb   = (bf16*)alloc((size_t)ROWS_T * HM * 2);   // all experts + shared
  } else if (tier == 2) {
    wgT  = (bf16*)alloc(WB);         // per-expert gate/up slots (also used for shared)
    wuT  = (bf16*)alloc(WB);
    wdT  = (bf16*)alloc(7 * WB);     // ALL routed down-weights resident
    swdT = (bf16*)alloc(WB);
    swgT = wgT; swuT = wuT;
    hb   = (bf16*)alloc((size_t)ROWS_R * HM * 2);   // all routed rows (shared uses prefix)
  } else {
    wgT  = (bf16*)alloc(WB);         // single-expert slots, reused
    wuT  = (bf16*)alloc(WB);
    wdT  = (bf16*)alloc(WB);
    swgT = wgT; swuT = wuT; swdT = wdT;
    hb   = (bf16*)alloc((size_t)NTOK * HM * 2);     // one expert (worst case all tokens)
  }
  yb = (bf16*)alloc((size_t)ROWS_T * DM * 2);
  int* cursor     = (int*)alloc(8 * 4);
  int* segs       = (int*)alloc(16 * 4);
  int* t_idx      = (int*)alloc((size_t)NTOK * 2 * 4);
  int* row_of     = (int*)alloc((size_t)NTOK * 2 * 4);
  int* tok_of_row = (int*)alloc((size_t)ROWS_T * 4);
  float* t_w      = (float*)alloc((size_t)NTOK * 2 * 4);
  if ((size_t)(p - (char*)d_ws) > ws_size) {
    fprintf(stderr, "MoE kernel: ws too small: need %zu have %zu (tier=%d)\n",
            (size_t)(p - (char*)d_ws), ws_size, tier);
    return;  // refuse to launch OOB — fails validation instead of crashing
  }

  hipMemsetAsync(cursor, 0, 8 * 4, stream);

  cvt_bf16_kernel<<<(NTOK * DM) / 1024, 256, 0, stream>>>(x, xb, NTOK * DM);
  router_kernel<<<NTOK / 4, 256, 0, stream>>>(x, router_w, t_idx, t_w);
  hist_kernel<<<1, 1024, 0, stream>>>(t_idx, segs);
  fill_kernel<<<NTOK / 256, 256, 0, stream>>>(t_idx, cursor, segs, tok_of_row, row_of);

  const dim3 tb(32, 8);
  const size_t WE = WEXP_ELEMS;

  if (tier == 1) {
    transpose_cvt_kernel<<<dim3(HM / 32, DM / 32, NE), tb, 0, stream>>>(w_gate, wgT, DM, HM);
    transpose_cvt_kernel<<<dim3(HM / 32, DM / 32, NE), tb, 0, stream>>>(w_up, wuT, DM, HM);
    transpose_cvt_kernel<<<dim3(DM / 32, HM / 32, NE), tb, 0, stream>>>(w_down, wdT, HM, DM);
    transpose_cvt3<<<dim3(4096, 1, 3), tb, 0, stream>>>(sw_gate, sw_up, sw_down,
                                                        swgT, swuT, swdT);
    gemm1_kernel<<<dim3(HM / 64, 64, 8), 256, 0, stream>>>(
        xb, wgT, wuT, swgT, swuT, segs, tok_of_row, hb, -1, 0, 0);
    gemm2_kernel<<<dim3(DM / 128, 64, 8), 256, 0, stream>>>(
        hb, wdT, swdT, segs, yb, -1, 0, 0);
  } else if (tier == 2) {
    // ---- tier-1.5: shared first (compact hb prefix), then routed experts into full hb,
    //      then ONE batched gemm2 over all routed experts. ----
    transpose_cvt_pair<<<dim3(HM / 32, DM / 32, 2), tb, 0, stream>>>(
        sw_gate, sw_up, wgT, wuT, DM, HM);
    gemm1_kernel<<<dim3(HM / 64, 64, 1), 256, 0, stream>>>(
        xb, wgT, wuT, wgT, wuT, segs, tok_of_row, hb, 7, 1, 1);
    transpose_cvt_wd<<<dim3(DM / 32, HM / 32, 8), tb, 0, stream>>>(
        w_down, sw_down, wdT, swdT);
    gemm2_kernel<<<dim3(DM / 128, 64, 1), 256, 0, stream>>>(
        hb, wdT, swdT, segs, yb, 7, 1, 1);
    for (int e = 0; e < NE; e++) {
      transpose_cvt_pair<<<dim3(HM / 32, DM / 32, 2), tb, 0, stream>>>(
          w_gate + (size_t)e * WE, w_up + (size_t)e * WE, wgT, wuT, DM, HM);
      gemm1_kernel<<<dim3(HM / 64, 64, 1), 256, 0, stream>>>(
          xb, wgT, wuT, wgT, wuT, segs, tok_of_row, hb, e, 1, 0);
    }
    gemm2_kernel<<<dim3(DM / 128, 64, 7), 256, 0, stream>>>(
        hb, wdT, swdT, segs, yb, -1, 0, 0);
  } else {
    // ---- tier-2: per-expert slot reuse, fused triple transposes ----
    transpose_cvt3<<<dim3(4096, 1, 3), tb, 0, stream>>>(sw_gate, sw_up, sw_down,
                                                        wgT, wuT, wdT);
    gemm1_kernel<<<dim3(HM / 64, 64, 1), 256, 0, stream>>>(
        xb, wgT, wuT, wgT, wuT, segs, tok_of_row, hb, 7, 1, 1);
    gemm2_kernel<<<dim3(DM / 128, 64, 1), 256, 0, stream>>>(
        hb, wdT, swdT, segs, yb, 7, 1, 1);
    for (int e = 0; e < NE; e++) {
      transpose_cvt3<<<dim3(4096, 1, 3), tb, 0, stream>>>(
          w_gate + (size_t)e * WE, w_up + (size_t)e * WE, w_down + (size_t)e * WE,
          wgT, wuT, wdT);
      gemm1_kernel<<<dim3(HM / 64, 64, 1), 256, 0, stream>>>(
          xb, wgT, wuT, wgT, wuT, segs, tok_of_row, hb, e, 1, 1);
      gemm2_kernel<<<dim3(DM / 128, 64, 1), 256, 0, stream>>>(
          hb, wdT, swdT, segs, yb, e, 1, 1);
    }
  }
  combine_kernel<<<NTOK, 256, 0, stream>>>(yb, row_of, t_w, out);
}

// Round 4
// 1354.015 us; speedup vs baseline: 1.3991x; 1.0446x over previous
//
#include <hip/hip_runtime.h>
#include <cstdint>
#include <cstdio>

#define DM 1024
#define HM 4096
#define NE 7
#define NTOK 8192
#define ROWS_R 16384   // 2*NTOK routed rows
#define ROWS_T 24576   // + NTOK shared rows
#define WEXP_ELEMS ((size_t)HM * DM)

typedef __bf16 bf16;
typedef __bf16 bf16x8 __attribute__((ext_vector_type(8)));
typedef __bf16 bf16x4 __attribute__((ext_vector_type(4)));
typedef float f32x4 __attribute__((ext_vector_type(4)));
typedef unsigned int u32;

__device__ __forceinline__ void gload_lds16(const bf16* g, bf16* l) {
  __builtin_amdgcn_global_load_lds((const __attribute__((address_space(1))) u32*)g,
                                   (__attribute__((address_space(3))) u32*)l, 16, 0, 0);
}

// ---------------- fp32 -> bf16 straight convert (x) ----------------
__global__ void cvt_bf16_kernel(const float* __restrict__ in, bf16* __restrict__ out, int n) {
  int i = (blockIdx.x * 256 + threadIdx.x) * 4;
  if (i >= n) return;
  float4 v = *(const float4*)(in + i);
  bf16x4 o; o[0] = (bf16)v.x; o[1] = (bf16)v.y; o[2] = (bf16)v.z; o[3] = (bf16)v.w;
  *(bf16x4*)(out + i) = o;
}

// ---------------- shared transpose tile body ----------------
__device__ __forceinline__ void transpose_tile(const float* __restrict__ ib,
                                               bf16* __restrict__ ob,
                                               int R, int C, int bx, int by,
                                               int tx, int ty) {
  __shared__ float tile[32][33];
  int c0 = bx * 32, r0 = by * 32;
  #pragma unroll
  for (int i = 0; i < 32; i += 8)
    tile[ty + i][tx] = ib[(size_t)(r0 + ty + i) * C + c0 + tx];
  __syncthreads();
  #pragma unroll
  for (int i = 0; i < 32; i += 8)
    ob[(size_t)(c0 + ty + i) * R + r0 + tx] = (bf16)tile[tx][ty + i];
}

// ---------------- fp32 [R][C] -> bf16 [C][R], z strides through experts ----------------
__global__ void transpose_cvt_kernel(const float* __restrict__ in, bf16* __restrict__ out,
                                     int R, int C) {
  const float* ib = in + (size_t)blockIdx.z * R * C;
  bf16* ob = out + (size_t)blockIdx.z * R * C;
  transpose_tile(ib, ob, R, C, blockIdx.x, blockIdx.y, threadIdx.x, threadIdx.y);
}

// ---------------- pair transpose: z=0 -> (s0,d0), z=1 -> (s1,d1), same R,C ----------------
__global__ void transpose_cvt_pair(const float* __restrict__ s0, const float* __restrict__ s1,
                                   bf16* __restrict__ d0, bf16* __restrict__ d1,
                                   int R, int C) {
  const float* ib = blockIdx.z ? s1 : s0;
  bf16* ob = blockIdx.z ? d1 : d0;
  transpose_tile(ib, ob, R, C, blockIdx.x, blockIdx.y, threadIdx.x, threadIdx.y);
}

// ---------------- w_down batch transpose: z<7 routed expert z, z==7 shared ----------------
__global__ void transpose_cvt_wd(const float* __restrict__ wd, const float* __restrict__ swd,
                                 bf16* __restrict__ wdT, bf16* __restrict__ swdT) {
  int z = blockIdx.z;
  const float* ib = (z < NE) ? wd + (size_t)z * WEXP_ELEMS : swd;
  bf16* ob = (z < NE) ? wdT + (size_t)z * WEXP_ELEMS : swdT;
  transpose_tile(ib, ob, HM, DM, blockIdx.x, blockIdx.y, threadIdx.x, threadIdx.y);
}

// ---------------- triple transpose: z=0 gate, z=1 up (DMxHM), z=2 down (HMxDM) ----
__global__ void transpose_cvt3(const float* __restrict__ g, const float* __restrict__ u,
                               const float* __restrict__ d,
                               bf16* __restrict__ og, bf16* __restrict__ ou,
                               bf16* __restrict__ od) {
  int z = blockIdx.z;
  int R = (z == 2) ? HM : DM, C = (z == 2) ? DM : HM;
  int nbx = C / 32;
  int bid = blockIdx.x;
  int bx = bid % nbx, by = bid / nbx;
  const float* ib = (z == 0) ? g : ((z == 1) ? u : d);
  bf16* ob = (z == 0) ? og : ((z == 1) ? ou : od);
  transpose_tile(ib, ob, R, C, bx, by, threadIdx.x, threadIdx.y);
}

// ---------------- router: logits, top-2, softmax (NO atomics) ----------------
__global__ __launch_bounds__(256) void router_kernel(
    const float* __restrict__ x, const float* __restrict__ rw,
    int* __restrict__ t_idx, float* __restrict__ t_w) {
  int wave = threadIdx.x >> 6, lane = threadIdx.x & 63;
  int t = blockIdx.x * 4 + wave;
  float acc[NE];
  #pragma unroll
  for (int e = 0; e < NE; e++) acc[e] = 0.f;
  const float* xr = x + (size_t)t * DM;
  for (int i = lane; i < DM; i += 64) {
    float xv = xr[i];
    #pragma unroll
    for (int e = 0; e < NE; e++) acc[e] += xv * rw[e * DM + i];
  }
  #pragma unroll
  for (int e = 0; e < NE; e++) {
    float v = acc[e];
    #pragma unroll
    for (int s = 32; s > 0; s >>= 1) v += __shfl_xor(v, s, 64);
    acc[e] = v;
  }
  if (lane == 0) {
    int b0 = 0; float v0 = acc[0];
    #pragma unroll
    for (int e = 1; e < NE; e++) if (acc[e] > v0) { v0 = acc[e]; b0 = e; }
    int b1 = -1; float v1 = -3.0e38f;
    #pragma unroll
    for (int e = 0; e < NE; e++) if (e != b0 && acc[e] > v1) { v1 = acc[e]; b1 = e; }
    float p0 = 1.f / (1.f + __expf(v1 - v0));  // softmax over top-2 (v0 >= v1)
    t_idx[t * 2] = b0; t_idx[t * 2 + 1] = b1;
    t_w[t * 2] = p0;  t_w[t * 2 + 1] = 1.f - p0;
  }
}

// ---------------- histogram + prefix: counts from t_idx, single block ----------------
__global__ __launch_bounds__(1024) void hist_kernel(const int* __restrict__ t_idx,
                                                    int* __restrict__ segs) {
  const int tid = threadIdx.x, wave = tid >> 6, lane = tid & 63;
  int c[NE];
  #pragma unroll
  for (int e = 0; e < NE; e++) c[e] = 0;
  for (int i = tid; i < NTOK * 2; i += 1024) {
    int e = t_idx[i];
    #pragma unroll
    for (int k = 0; k < NE; k++) c[k] += (e == k) ? 1 : 0;
  }
  __shared__ int ws[16][8];
  #pragma unroll
  for (int k = 0; k < NE; k++) {
    int v = c[k];
    #pragma unroll
    for (int s = 32; s > 0; s >>= 1) v += __shfl_xor(v, s, 64);
    if (lane == 0) ws[wave][k] = v;
  }
  __syncthreads();
  if (tid == 0) {
    int o = 0;
    for (int e = 0; e < NE; e++) {
      int cnt = 0;
      for (int w = 0; w < 16; w++) cnt += ws[w][e];
      segs[e] = o; segs[8 + e] = cnt; o += cnt;
    }
    segs[7] = ROWS_R;   // shared expert segment
    segs[15] = NTOK;
  }
}

// ---------------- fill per-expert row lists: ballot rank + 1 atomic/(block,expert) ----------------
__global__ __launch_bounds__(256) void fill_kernel(
    const int* __restrict__ t_idx, int* __restrict__ cursor,
    const int* __restrict__ segs, int* __restrict__ tok_of_row,
    int* __restrict__ row_of) {
  __shared__ int wcnt[2][4][8];   // [slot][wave][expert] counts
  __shared__ int wbase[2][4][8];  // [slot][wave][expert] intra-block offsets
  __shared__ int bbase[8];        // block base row per expert
  const int tid = threadIdx.x, wave = tid >> 6, lane = tid & 63;
  const int t = blockIdx.x * 256 + tid;
  const int e0 = t_idx[t * 2], e1 = t_idx[t * 2 + 1];
  const unsigned long long lt = (1ull << lane) - 1ull;
  int rank0 = 0, rank1 = 0;
  #pragma unroll
  for (int e = 0; e < NE; e++) {
    unsigned long long m0 = __ballot(e0 == e);
    unsigned long long m1 = __ballot(e1 == e);
    if (e0 == e) rank0 = __popcll(m0 & lt);
    if (e1 == e) rank1 = __popcll(m1 & lt);
    if (lane == 0) { wcnt[0][wave][e] = __popcll(m0); wcnt[1][wave][e] = __popcll(m1); }
  }
  __syncthreads();
  if (tid < NE) {
    int e = tid, run = 0;
    #pragma unroll
    for (int s = 0; s < 2; s++)
      #pragma unroll
      for (int w = 0; w < 4; w++) { wbase[s][w][e] = run; run += wcnt[s][w][e]; }
    bbase[e] = segs[e] + atomicAdd(&cursor[e], run);
  }
  __syncthreads();
  int r0 = bbase[e0] + wbase[0][wave][e0] + rank0;
  int r1 = bbase[e1] + wbase[1][wave][e1] + rank1;
  tok_of_row[r0] = t;  row_of[t * 2] = r0;
  tok_of_row[r1] = t;  row_of[t * 2 + 1] = r1;
  tok_of_row[ROWS_R + t] = t;  // shared segment: identity
}

// ---------------- GEMM1: h = silu(x@Wg) * (x@Wu), gathered rows ----------------
// BM=128 BN=64 BK=32; 4 waves, each 64rows x 32cols per matrix; two B matrices fused.
__global__ __launch_bounds__(256, 2) void gemm1_kernel(
    const bf16* __restrict__ xb, const bf16* __restrict__ wgT, const bf16* __restrict__ wuT,
    const bf16* __restrict__ swgT, const bf16* __restrict__ swuT,
    const int* __restrict__ segs, const int* __restrict__ tok_of_row,
    bf16* __restrict__ hb, int e_fixed, int wcompact, int hcompact) {
  const int e = (e_fixed >= 0) ? e_fixed : (int)blockIdx.z;
  const int off = segs[e], cnt = segs[8 + e];
  const int hoff = hcompact ? 0 : off;
  const int r0 = blockIdx.y * 128;
  if (r0 >= cnt) return;
  const int n0 = blockIdx.x * 64;
  const size_t estride = wcompact ? 0 : (size_t)e * WEXP_ELEMS;
  const bf16* bg = (e < NE) ? wgT + estride : swgT;
  const bf16* bu = (e < NE) ? wuT + estride : swuT;

  __shared__ __align__(16) bf16 As[128 * 32];
  __shared__ __align__(16) bf16 Bgs[64 * 32];
  __shared__ __align__(16) bf16 Bus[64 * 32];

  const int tid = threadIdx.x, wave = tid >> 6, lane = tid & 63;
  int lr0 = wave * 16 + (lane >> 2);
  int lr1 = lr0 + 64;
  int i0 = min(r0 + lr0, cnt - 1);
  int i1 = min(r0 + lr1, cnt - 1);
  const bf16* agp0 = xb + (size_t)tok_of_row[off + i0] * DM + (lane & 3) * 8;
  const bf16* agp1 = xb + (size_t)tok_of_row[off + i1] * DM + (lane & 3) * 8;
  const bf16* bgp = bg + (size_t)(n0 + lr0) * DM + (lane & 3) * 8;
  const bf16* bup = bu + (size_t)(n0 + lr0) * DM + (lane & 3) * 8;
  bf16* As_w0 = &As[wave * 512];
  bf16* As_w1 = &As[(4 + wave) * 512];
  bf16* Bgs_w = &Bgs[wave * 512];
  bf16* Bus_w = &Bus[wave * 512];

  const int wr = wave & 1, wc = wave >> 1;
  const int mbase = wr * 64, nbase = wc * 32;
  const int fl = lane & 15, fq = lane >> 4;
  f32x4 accg[4][2] = {}; f32x4 accu[4][2] = {};

  for (int k0 = 0; k0 < DM; k0 += 32) {
    gload_lds16(agp0 + k0, As_w0);
    gload_lds16(agp1 + k0, As_w1);
    gload_lds16(bgp + k0, Bgs_w);
    gload_lds16(bup + k0, Bus_w);
    __syncthreads();
    bf16x8 af[4], bgf[2], buf[2];
    #pragma unroll
    for (int i = 0; i < 4; i++)
      af[i] = *(const bf16x8*)&As[(mbase + i * 16 + fl) * 32 + fq * 8];
    #pragma unroll
    for (int j = 0; j < 2; j++) {
      bgf[j] = *(const bf16x8*)&Bgs[(nbase + j * 16 + fl) * 32 + fq * 8];
      buf[j] = *(const bf16x8*)&Bus[(nbase + j * 16 + fl) * 32 + fq * 8];
    }
    #pragma unroll
    for (int i = 0; i < 4; i++)
      #pragma unroll
      for (int j = 0; j < 2; j++) {
        accg[i][j] = __builtin_amdgcn_mfma_f32_16x16x32_bf16(af[i], bgf[j], accg[i][j], 0, 0, 0);
        accu[i][j] = __builtin_amdgcn_mfma_f32_16x16x32_bf16(af[i], buf[j], accu[i][j], 0, 0, 0);
      }
    __syncthreads();
  }
  #pragma unroll
  for (int i = 0; i < 4; i++)
    #pragma unroll
    for (int j = 0; j < 2; j++)
      #pragma unroll
      for (int r = 0; r < 4; r++) {
        int lr = mbase + i * 16 + fq * 4 + r;
        if (r0 + lr < cnt) {
          float g = accg[i][j][r], u = accu[i][j][r];
          float s = g / (1.f + __expf(-g));
          int col = n0 + nbase + j * 16 + fl;
          hb[(size_t)(hoff + r0 + lr) * HM + col] = (bf16)(s * u);
        }
      }
}

// ---------------- GEMM2: y = h @ Wd ----------------
// BM=128 BN=256 BK=32; 4 waves (2M x 2N), each 64x128. Halves A-panel refetch vs BN=128.
__global__ __launch_bounds__(256, 2) void gemm2_kernel(
    const bf16* __restrict__ hb, const bf16* __restrict__ wdT, const bf16* __restrict__ swdT,
    const int* __restrict__ segs, bf16* __restrict__ yb, int e_fixed, int wcompact,
    int hcompact) {
  const int e = (e_fixed >= 0) ? e_fixed : (int)blockIdx.z;
  const int off = segs[e], cnt = segs[8 + e];
  const int hoff = hcompact ? 0 : off;
  const int r0 = blockIdx.y * 128;
  if (r0 >= cnt) return;
  const int n0 = blockIdx.x * 256;
  const size_t estride = wcompact ? 0 : (size_t)e * WEXP_ELEMS;
  const bf16* bd = (e < NE) ? wdT + estride : swdT;

  __shared__ __align__(16) bf16 As[128 * 32];
  __shared__ __align__(16) bf16 Bs[256 * 32];

  const int tid = threadIdx.x, wave = tid >> 6, lane = tid & 63;
  int lr0 = wave * 16 + (lane >> 2);
  int i0 = min(r0 + lr0, cnt - 1);
  int i1 = min(r0 + lr0 + 64, cnt - 1);
  const bf16* agp0 = hb + (size_t)(hoff + i0) * HM + (lane & 3) * 8;
  const bf16* agp1 = hb + (size_t)(hoff + i1) * HM + (lane & 3) * 8;
  const bf16* bgp0 = bd + (size_t)(n0 + lr0) * HM + (lane & 3) * 8;
  bf16* As_w0 = &As[wave * 512];
  bf16* As_w1 = &As[(4 + wave) * 512];
  bf16* Bs_w0 = &Bs[wave * 512];            // rows wave*16 + {0,64,128,192}
  bf16* Bs_w1 = &Bs[wave * 512 + 2048];
  bf16* Bs_w2 = &Bs[wave * 512 + 4096];
  bf16* Bs_w3 = &Bs[wave * 512 + 6144];

  const int wr = wave & 1, wc = wave >> 1;
  const int mbase = wr * 64, nbase = wc * 128;
  const int fl = lane & 15, fq = lane >> 4;
  f32x4 acc[4][8] = {};

  for (int k0 = 0; k0 < HM; k0 += 32) {
    gload_lds16(agp0 + k0, As_w0);
    gload_lds16(agp1 + k0, As_w1);
    gload_lds16(bgp0 + k0, Bs_w0);
    gload_lds16(bgp0 + (size_t)64 * HM + k0, Bs_w1);
    gload_lds16(bgp0 + (size_t)128 * HM + k0, Bs_w2);
    gload_lds16(bgp0 + (size_t)192 * HM + k0, Bs_w3);
    __syncthreads();
    bf16x8 af[4], bfv[8];
    #pragma unroll
    for (int i = 0; i < 4; i++)
      af[i] = *(const bf16x8*)&As[(mbase + i * 16 + fl) * 32 + fq * 8];
    #pragma unroll
    for (int j = 0; j < 8; j++)
      bfv[j] = *(const bf16x8*)&Bs[(nbase + j * 16 + fl) * 32 + fq * 8];
    #pragma unroll
    for (int i = 0; i < 4; i++)
      #pragma unroll
      for (int j = 0; j < 8; j++)
        acc[i][j] = __builtin_amdgcn_mfma_f32_16x16x32_bf16(af[i], bfv[j], acc[i][j], 0, 0, 0);
    __syncthreads();
  }
  #pragma unroll
  for (int i = 0; i < 4; i++)
    #pragma unroll
    for (int j = 0; j < 8; j++)
      #pragma unroll
      for (int r = 0; r < 4; r++) {
        int lr = mbase + i * 16 + fq * 4 + r;
        if (r0 + lr < cnt) {
          int col = n0 + nbase + j * 16 + fl;
          yb[(size_t)(off + r0 + lr) * DM + col] = (bf16)acc[i][j][r];
        }
      }
}

// ---------------- combine: out = w0*y[r0] + w1*y[r1] + y[shared] ----------------
__global__ __launch_bounds__(256) void combine_kernel(
    const bf16* __restrict__ yb, const int* __restrict__ row_of,
    const float* __restrict__ t_w, float* __restrict__ out) {
  int t = blockIdx.x;
  int d = threadIdx.x * 4;
  int r0 = row_of[t * 2], r1 = row_of[t * 2 + 1];
  float w0 = t_w[t * 2], w1 = t_w[t * 2 + 1];
  bf16x4 a = *(const bf16x4*)&yb[(size_t)r0 * DM + d];
  bf16x4 b = *(const bf16x4*)&yb[(size_t)r1 * DM + d];
  bf16x4 c = *(const bf16x4*)&yb[(size_t)(ROWS_R + t) * DM + d];
  float4 o;
  o.x = w0 * (float)a[0] + w1 * (float)b[0] + (float)c[0];
  o.y = w0 * (float)a[1] + w1 * (float)b[1] + (float)c[1];
  o.z = w0 * (float)a[2] + w1 * (float)b[2] + (float)c[2];
  o.w = w0 * (float)a[3] + w1 * (float)b[3] + (float)c[3];
  *(float4*)&out[(size_t)t * DM + d] = o;
}

extern "C" void kernel_launch(void* const* d_in, const int* in_sizes, int n_in,
                              void* d_out, int out_size, void* d_ws, size_t ws_size,
                              hipStream_t stream) {
  const float* x        = (const float*)d_in[0];
  const float* router_w = (const float*)d_in[1];
  const float* w_gate   = (const float*)d_in[2];
  const float* w_up     = (const float*)d_in[3];
  const float* w_down   = (const float*)d_in[4];
  const float* sw_gate  = (const float*)d_in[5];
  const float* sw_up    = (const float*)d_in[6];
  const float* sw_down  = (const float*)d_in[7];
  float* out = (float*)d_out;

  const size_t WB = WEXP_ELEMS * 2;              // bytes per expert weight matrix (bf16)
  const size_t MISC = (size_t)2 << 20;
  const size_t NEED_T1  = (size_t)NTOK * DM * 2 + 21 * WB + 3 * WB +
                          (size_t)ROWS_T * HM * 2 + (size_t)ROWS_T * DM * 2 + MISC;
  const size_t NEED_T14 = (size_t)NTOK * DM * 2 + 21 * WB + 3 * WB +
                          (size_t)ROWS_R * HM * 2 + (size_t)ROWS_T * DM * 2 + MISC;
  const size_t NEED_T15 = (size_t)NTOK * DM * 2 + 2 * WB + 8 * WB +
                          (size_t)ROWS_R * HM * 2 + (size_t)ROWS_T * DM * 2 + MISC;
  const int tier = (ws_size >= NEED_T1 + (16 << 20))  ? 1
                 : (ws_size >= NEED_T14 + (8 << 20))  ? 14
                 : (ws_size >= NEED_T15 + (8 << 20))  ? 15 : 2;

  char* p = (char*)d_ws;
  auto alloc = [&](size_t bytes) { char* r = p; p += (bytes + 255) & ~(size_t)255; return r; };

  bf16* xb = (bf16*)alloc((size_t)NTOK * DM * 2);
  bf16 *wgT, *wuT, *wdT, *swgT, *swuT, *swdT, *hb, *yb;
  if (tier == 1 || tier == 14) {
    wgT  = (bf16*)alloc(7 * WB);
    wuT  = (bf16*)alloc(7 * WB);
    wdT  = (bf16*)alloc(7 * WB);
    swgT = (bf16*)alloc(WB);
    swuT = (bf16*)alloc(WB);
    swdT = (bf16*)alloc(WB);
    hb   = (bf16*)alloc((tier == 1 ? (size_t)ROWS_T : (size_t)ROWS_R) * HM * 2);
  } else if (tier == 15) {
    wgT  = (bf16*)alloc(WB);         // per-expert gate/up slots (also used for shared)
    wuT  = (bf16*)alloc(WB);
    wdT  = (bf16*)alloc(7 * WB);     // ALL routed down-weights resident
    swdT = (bf16*)alloc(WB);
    swgT = wgT; swuT = wuT;
    hb   = (bf16*)alloc((size_t)ROWS_R * HM * 2);   // all routed rows (shared uses prefix)
  } else {
    wgT  = (bf16*)alloc(WB);         // single-expert slots, reused
    wuT  = (bf16*)alloc(WB);
    wdT  = (bf16*)alloc(WB);
    swgT = wgT; swuT = wuT; swdT = wdT;
    hb   = (bf16*)alloc((size_t)NTOK * HM * 2);     // one expert (worst case all tokens)
  }
  yb = (bf16*)alloc((size_t)ROWS_T * DM * 2);
  int* cursor     = (int*)alloc(8 * 4);
  int* segs       = (int*)alloc(16 * 4);
  int* t_idx      = (int*)alloc((size_t)NTOK * 2 * 4);
  int* row_of     = (int*)alloc((size_t)NTOK * 2 * 4);
  int* tok_of_row = (int*)alloc((size_t)ROWS_T * 4);
  float* t_w      = (float*)alloc((size_t)NTOK * 2 * 4);
  if ((size_t)(p - (char*)d_ws) > ws_size) {
    fprintf(stderr, "MoE kernel: ws too small: need %zu have %zu (tier=%d)\n",
            (size_t)(p - (char*)d_ws), ws_size, tier);
    return;  // refuse to launch OOB — fails validation instead of crashing
  }

  hipMemsetAsync(cursor, 0, 8 * 4, stream);

  cvt_bf16_kernel<<<(NTOK * DM) / 1024, 256, 0, stream>>>(x, xb, NTOK * DM);
  router_kernel<<<NTOK / 4, 256, 0, stream>>>(x, router_w, t_idx, t_w);
  hist_kernel<<<1, 1024, 0, stream>>>(t_idx, segs);
  fill_kernel<<<NTOK / 256, 256, 0, stream>>>(t_idx, cursor, segs, tok_of_row, row_of);

  const dim3 tb(32, 8);
  const size_t WE = WEXP_ELEMS;

  if (tier == 1) {
    transpose_cvt_kernel<<<dim3(HM / 32, DM / 32, NE), tb, 0, stream>>>(w_gate, wgT, DM, HM);
    transpose_cvt_kernel<<<dim3(HM / 32, DM / 32, NE), tb, 0, stream>>>(w_up, wuT, DM, HM);
    transpose_cvt_wd<<<dim3(DM / 32, HM / 32, 8), tb, 0, stream>>>(w_down, sw_down, wdT, swdT);
    transpose_cvt_pair<<<dim3(HM / 32, DM / 32, 2), tb, 0, stream>>>(
        sw_gate, sw_up, swgT, swuT, DM, HM);
    gemm1_kernel<<<dim3(HM / 64, 64, 8), 256, 0, stream>>>(
        xb, wgT, wuT, swgT, swuT, segs, tok_of_row, hb, -1, 0, 0);
    gemm2_kernel<<<dim3(DM / 256, 64, 8), 256, 0, stream>>>(
        hb, wdT, swdT, segs, yb, -1, 0, 0);
  } else if (tier == 14) {
    // ---- tier-1.4: all weights transposed up front; shared pass uses hb prefix,
    //      then ONE batched gemm1 + ONE batched gemm2 over all routed experts. ----
    transpose_cvt_kernel<<<dim3(HM / 32, DM / 32, NE), tb, 0, stream>>>(w_gate, wgT, DM, HM);
    transpose_cvt_kernel<<<dim3(HM / 32, DM / 32, NE), tb, 0, stream>>>(w_up, wuT, DM, HM);
    transpose_cvt_wd<<<dim3(DM / 32, HM / 32, 8), tb, 0, stream>>>(w_down, sw_down, wdT, swdT);
    transpose_cvt_pair<<<dim3(HM / 32, DM / 32, 2), tb, 0, stream>>>(
        sw_gate, sw_up, swgT, swuT, DM, HM);
    gemm1_kernel<<<dim3(HM / 64, 64, 1), 256, 0, stream>>>(
        xb, wgT, wuT, swgT, swuT, segs, tok_of_row, hb, 7, 0, 1);
    gemm2_kernel<<<dim3(DM / 256, 64, 1), 256, 0, stream>>>(
        hb, wdT, swdT, segs, yb, 7, 0, 1);
    gemm1_kernel<<<dim3(HM / 64, 64, 7), 256, 0, stream>>>(
        xb, wgT, wuT, swgT, swuT, segs, tok_of_row, hb, -1, 0, 0);
    gemm2_kernel<<<dim3(DM / 256, 64, 7), 256, 0, stream>>>(
        hb, wdT, swdT, segs, yb, -1, 0, 0);
  } else if (tier == 15) {
    // ---- tier-1.5: shared first (compact hb prefix), then routed experts into full hb,
    //      then ONE batched gemm2 over all routed experts. ----
    transpose_cvt_pair<<<dim3(HM / 32, DM / 32, 2), tb, 0, stream>>>(
        sw_gate, sw_up, wgT, wuT, DM, HM);
    gemm1_kernel<<<dim3(HM / 64, 64, 1), 256, 0, stream>>>(
        xb, wgT, wuT, wgT, wuT, segs, tok_of_row, hb, 7, 1, 1);
    transpose_cvt_wd<<<dim3(DM / 32, HM / 32, 8), tb, 0, stream>>>(
        w_down, sw_down, wdT, swdT);
    gemm2_kernel<<<dim3(DM / 256, 64, 1), 256, 0, stream>>>(
        hb, wdT, swdT, segs, yb, 7, 1, 1);
    for (int e = 0; e < NE; e++) {
      transpose_cvt_pair<<<dim3(HM / 32, DM / 32, 2), tb, 0, stream>>>(
          w_gate + (size_t)e * WE, w_up + (size_t)e * WE, wgT, wuT, DM, HM);
      gemm1_kernel<<<dim3(HM / 64, 64, 1), 256, 0, stream>>>(
          xb, wgT, wuT, wgT, wuT, segs, tok_of_row, hb, e, 1, 0);
    }
    gemm2_kernel<<<dim3(DM / 256, 64, 7), 256, 0, stream>>>(
        hb, wdT, swdT, segs, yb, -1, 0, 0);
  } else {
    // ---- tier-2: per-expert slot reuse, fused triple transposes ----
    transpose_cvt3<<<dim3(4096, 1, 3), tb, 0, stream>>>(sw_gate, sw_up, sw_down,
                                                        wgT, wuT, wdT);
    gemm1_kernel<<<dim3(HM / 64, 64, 1), 256, 0, stream>>>(
        xb, wgT, wuT, wgT, wuT, segs, tok_of_row, hb, 7, 1, 1);
    gemm2_kernel<<<dim3(DM / 256, 64, 1), 256, 0, stream>>>(
        hb, wdT, swdT, segs, yb, 7, 1, 1);
    for (int e = 0; e < NE; e++) {
      transpose_cvt3<<<dim3(4096, 1, 3), tb, 0, stream>>>(
          w_gate + (size_t)e * WE, w_up + (size_t)e * WE, w_down + (size_t)e * WE,
          wgT, wuT, wdT);
      gemm1_kernel<<<dim3(HM / 64, 64, 1), 256, 0, stream>>>(
          xb, wgT, wuT, wgT, wuT, segs, tok_of_row, hb, e, 1, 1);
      gemm2_kernel<<<dim3(DM / 256, 64, 1), 256, 0, stream>>>(
          hb, wdT, swdT, segs, yb, e, 1, 1);
    }
  }
  combine_kernel<<<NTOK, 256, 0, stream>>>(yb, row_of, t_w, out);
}

// Round 5
// 1353.127 us; speedup vs baseline: 1.4000x; 1.0007x over previous
//
#include <hip/hip_runtime.h>
#include <cstdint>
#include <cstdio>

#define DM 1024
#define HM 4096
#define NE 7
#define NTOK 8192
#define ROWS_R 16384   // 2*NTOK routed rows
#define ROWS_T 24576   // + NTOK shared rows
#define WEXP_ELEMS ((size_t)HM * DM)

typedef __bf16 bf16;
typedef __bf16 bf16x8 __attribute__((ext_vector_type(8)));
typedef __bf16 bf16x4 __attribute__((ext_vector_type(4)));
typedef float f32x4 __attribute__((ext_vector_type(4)));
typedef unsigned int u32;

__device__ __forceinline__ void gload_lds16(const bf16* g, bf16* l) {
  __builtin_amdgcn_global_load_lds((const __attribute__((address_space(1))) u32*)g,
                                   (__attribute__((address_space(3))) u32*)l, 16, 0, 0);
}

// ---------------- fp32 -> bf16 straight convert (x) ----------------
__global__ void cvt_bf16_kernel(const float* __restrict__ in, bf16* __restrict__ out, int n) {
  int i = (blockIdx.x * 256 + threadIdx.x) * 4;
  if (i >= n) return;
  float4 v = *(const float4*)(in + i);
  bf16x4 o; o[0] = (bf16)v.x; o[1] = (bf16)v.y; o[2] = (bf16)v.z; o[3] = (bf16)v.w;
  *(bf16x4*)(out + i) = o;
}

// ---------------- shared transpose tile body ----------------
__device__ __forceinline__ void transpose_tile(const float* __restrict__ ib,
                                               bf16* __restrict__ ob,
                                               int R, int C, int bx, int by,
                                               int tx, int ty) {
  __shared__ float tile[32][33];
  int c0 = bx * 32, r0 = by * 32;
  #pragma unroll
  for (int i = 0; i < 32; i += 8)
    tile[ty + i][tx] = ib[(size_t)(r0 + ty + i) * C + c0 + tx];
  __syncthreads();
  #pragma unroll
  for (int i = 0; i < 32; i += 8)
    ob[(size_t)(c0 + ty + i) * R + r0 + tx] = (bf16)tile[tx][ty + i];
}

// ---------------- fp32 [R][C] -> bf16 [C][R], z strides through experts ----------------
__global__ void transpose_cvt_kernel(const float* __restrict__ in, bf16* __restrict__ out,
                                     int R, int C) {
  const float* ib = in + (size_t)blockIdx.z * R * C;
  bf16* ob = out + (size_t)blockIdx.z * R * C;
  transpose_tile(ib, ob, R, C, blockIdx.x, blockIdx.y, threadIdx.x, threadIdx.y);
}

// ---------------- pair transpose: z=0 -> (s0,d0), z=1 -> (s1,d1), same R,C ----------------
__global__ void transpose_cvt_pair(const float* __restrict__ s0, const float* __restrict__ s1,
                                   bf16* __restrict__ d0, bf16* __restrict__ d1,
                                   int R, int C) {
  const float* ib = blockIdx.z ? s1 : s0;
  bf16* ob = blockIdx.z ? d1 : d0;
  transpose_tile(ib, ob, R, C, blockIdx.x, blockIdx.y, threadIdx.x, threadIdx.y);
}

// ---------------- w_down batch transpose: z<7 routed expert z, z==7 shared ----------------
__global__ void transpose_cvt_wd(const float* __restrict__ wd, const float* __restrict__ swd,
                                 bf16* __restrict__ wdT, bf16* __restrict__ swdT) {
  int z = blockIdx.z;
  const float* ib = (z < NE) ? wd + (size_t)z * WEXP_ELEMS : swd;
  bf16* ob = (z < NE) ? wdT + (size_t)z * WEXP_ELEMS : swdT;
  transpose_tile(ib, ob, HM, DM, blockIdx.x, blockIdx.y, threadIdx.x, threadIdx.y);
}

// ---------------- triple transpose: z=0 gate, z=1 up (DMxHM), z=2 down (HMxDM) ----
__global__ void transpose_cvt3(const float* __restrict__ g, const float* __restrict__ u,
                               const float* __restrict__ d,
                               bf16* __restrict__ og, bf16* __restrict__ ou,
                               bf16* __restrict__ od) {
  int z = blockIdx.z;
  int R = (z == 2) ? HM : DM, C = (z == 2) ? DM : HM;
  int nbx = C / 32;
  int bid = blockIdx.x;
  int bx = bid % nbx, by = bid / nbx;
  const float* ib = (z == 0) ? g : ((z == 1) ? u : d);
  bf16* ob = (z == 0) ? og : ((z == 1) ? ou : od);
  transpose_tile(ib, ob, R, C, bx, by, threadIdx.x, threadIdx.y);
}

// ---------------- router: logits, top-2, softmax (NO atomics) ----------------
__global__ __launch_bounds__(256) void router_kernel(
    const float* __restrict__ x, const float* __restrict__ rw,
    int* __restrict__ t_idx, float* __restrict__ t_w) {
  int wave = threadIdx.x >> 6, lane = threadIdx.x & 63;
  int t = blockIdx.x * 4 + wave;
  float acc[NE];
  #pragma unroll
  for (int e = 0; e < NE; e++) acc[e] = 0.f;
  const float* xr = x + (size_t)t * DM;
  for (int i = lane; i < DM; i += 64) {
    float xv = xr[i];
    #pragma unroll
    for (int e = 0; e < NE; e++) acc[e] += xv * rw[e * DM + i];
  }
  #pragma unroll
  for (int e = 0; e < NE; e++) {
    float v = acc[e];
    #pragma unroll
    for (int s = 32; s > 0; s >>= 1) v += __shfl_xor(v, s, 64);
    acc[e] = v;
  }
  if (lane == 0) {
    int b0 = 0; float v0 = acc[0];
    #pragma unroll
    for (int e = 1; e < NE; e++) if (acc[e] > v0) { v0 = acc[e]; b0 = e; }
    int b1 = -1; float v1 = -3.0e38f;
    #pragma unroll
    for (int e = 0; e < NE; e++) if (e != b0 && acc[e] > v1) { v1 = acc[e]; b1 = e; }
    float p0 = 1.f / (1.f + __expf(v1 - v0));  // softmax over top-2 (v0 >= v1)
    t_idx[t * 2] = b0; t_idx[t * 2 + 1] = b1;
    t_w[t * 2] = p0;  t_w[t * 2 + 1] = 1.f - p0;
  }
}

// ---------------- histogram + prefix: counts from t_idx, single block ----------------
__global__ __launch_bounds__(1024) void hist_kernel(const int* __restrict__ t_idx,
                                                    int* __restrict__ segs) {
  const int tid = threadIdx.x, wave = tid >> 6, lane = tid & 63;
  int c[NE];
  #pragma unroll
  for (int e = 0; e < NE; e++) c[e] = 0;
  for (int i = tid; i < NTOK * 2; i += 1024) {
    int e = t_idx[i];
    #pragma unroll
    for (int k = 0; k < NE; k++) c[k] += (e == k) ? 1 : 0;
  }
  __shared__ int ws[16][8];
  #pragma unroll
  for (int k = 0; k < NE; k++) {
    int v = c[k];
    #pragma unroll
    for (int s = 32; s > 0; s >>= 1) v += __shfl_xor(v, s, 64);
    if (lane == 0) ws[wave][k] = v;
  }
  __syncthreads();
  if (tid == 0) {
    int o = 0;
    for (int e = 0; e < NE; e++) {
      int cnt = 0;
      for (int w = 0; w < 16; w++) cnt += ws[w][e];
      segs[e] = o; segs[8 + e] = cnt; o += cnt;
    }
    segs[7] = ROWS_R;   // shared expert segment
    segs[15] = NTOK;
  }
}

// ---------------- fill per-expert row lists: ballot rank + 1 atomic/(block,expert) ----------------
__global__ __launch_bounds__(256) void fill_kernel(
    const int* __restrict__ t_idx, int* __restrict__ cursor,
    const int* __restrict__ segs, int* __restrict__ tok_of_row,
    int* __restrict__ row_of) {
  __shared__ int wcnt[2][4][8];   // [slot][wave][expert] counts
  __shared__ int wbase[2][4][8];  // [slot][wave][expert] intra-block offsets
  __shared__ int bbase[8];        // block base row per expert
  const int tid = threadIdx.x, wave = tid >> 6, lane = tid & 63;
  const int t = blockIdx.x * 256 + tid;
  const int e0 = t_idx[t * 2], e1 = t_idx[t * 2 + 1];
  const unsigned long long lt = (1ull << lane) - 1ull;
  int rank0 = 0, rank1 = 0;
  #pragma unroll
  for (int e = 0; e < NE; e++) {
    unsigned long long m0 = __ballot(e0 == e);
    unsigned long long m1 = __ballot(e1 == e);
    if (e0 == e) rank0 = __popcll(m0 & lt);
    if (e1 == e) rank1 = __popcll(m1 & lt);
    if (lane == 0) { wcnt[0][wave][e] = __popcll(m0); wcnt[1][wave][e] = __popcll(m1); }
  }
  __syncthreads();
  if (tid < NE) {
    int e = tid, run = 0;
    #pragma unroll
    for (int s = 0; s < 2; s++)
      #pragma unroll
      for (int w = 0; w < 4; w++) { wbase[s][w][e] = run; run += wcnt[s][w][e]; }
    bbase[e] = segs[e] + atomicAdd(&cursor[e], run);
  }
  __syncthreads();
  int r0 = bbase[e0] + wbase[0][wave][e0] + rank0;
  int r1 = bbase[e1] + wbase[1][wave][e1] + rank1;
  tok_of_row[r0] = t;  row_of[t * 2] = r0;
  tok_of_row[r1] = t;  row_of[t * 2 + 1] = r1;
  tok_of_row[ROWS_R + t] = t;  // shared segment: identity
}

// ---------------- GEMM1: h = silu(x@Wg) * (x@Wu), gathered rows ----------------
// BM=128 BN=128 (per matrix) BK=32; 4 waves (2M x 2N), each 64x64 of BOTH outputs.
// 32 MFMA / 12 ds_read / 6 stage per wave per K-step (was 16/8/4 at BN=64).
__global__ __launch_bounds__(256, 2) void gemm1_kernel(
    const bf16* __restrict__ xb, const bf16* __restrict__ wgT, const bf16* __restrict__ wuT,
    const bf16* __restrict__ swgT, const bf16* __restrict__ swuT,
    const int* __restrict__ segs, const int* __restrict__ tok_of_row,
    bf16* __restrict__ hb, int e_fixed, int wcompact, int hcompact) {
  const int e = (e_fixed >= 0) ? e_fixed : (int)blockIdx.z;
  const int off = segs[e], cnt = segs[8 + e];
  const int hoff = hcompact ? 0 : off;
  const int r0 = blockIdx.y * 128;
  if (r0 >= cnt) return;
  const int n0 = blockIdx.x * 128;
  const size_t estride = wcompact ? 0 : (size_t)e * WEXP_ELEMS;
  const bf16* bg = (e < NE) ? wgT + estride : swgT;
  const bf16* bu = (e < NE) ? wuT + estride : swuT;

  __shared__ __align__(16) bf16 As[128 * 32];
  __shared__ __align__(16) bf16 Bgs[128 * 32];
  __shared__ __align__(16) bf16 Bus[128 * 32];

  const int tid = threadIdx.x, wave = tid >> 6, lane = tid & 63;
  int lr0 = wave * 16 + (lane >> 2);
  int lr1 = lr0 + 64;
  int i0 = min(r0 + lr0, cnt - 1);
  int i1 = min(r0 + lr1, cnt - 1);
  const bf16* agp0 = xb + (size_t)tok_of_row[off + i0] * DM + (lane & 3) * 8;
  const bf16* agp1 = xb + (size_t)tok_of_row[off + i1] * DM + (lane & 3) * 8;
  const bf16* bgp0 = bg + (size_t)(n0 + lr0) * DM + (lane & 3) * 8;
  const bf16* bgp1 = bgp0 + (size_t)64 * DM;
  const bf16* bup0 = bu + (size_t)(n0 + lr0) * DM + (lane & 3) * 8;
  const bf16* bup1 = bup0 + (size_t)64 * DM;
  bf16* As_w0  = &As[wave * 512];
  bf16* As_w1  = &As[(4 + wave) * 512];
  bf16* Bgs_w0 = &Bgs[wave * 512];
  bf16* Bgs_w1 = &Bgs[(4 + wave) * 512];
  bf16* Bus_w0 = &Bus[wave * 512];
  bf16* Bus_w1 = &Bus[(4 + wave) * 512];

  const int wr = wave & 1, wc = wave >> 1;
  const int mbase = wr * 64, nbase = wc * 64;
  const int fl = lane & 15, fq = lane >> 4;
  f32x4 accg[4][4] = {}; f32x4 accu[4][4] = {};

  for (int k0 = 0; k0 < DM; k0 += 32) {
    gload_lds16(agp0 + k0, As_w0);
    gload_lds16(agp1 + k0, As_w1);
    gload_lds16(bgp0 + k0, Bgs_w0);
    gload_lds16(bgp1 + k0, Bgs_w1);
    gload_lds16(bup0 + k0, Bus_w0);
    gload_lds16(bup1 + k0, Bus_w1);
    __syncthreads();
    bf16x8 af[4], bgf[4], buf[4];
    #pragma unroll
    for (int i = 0; i < 4; i++)
      af[i] = *(const bf16x8*)&As[(mbase + i * 16 + fl) * 32 + fq * 8];
    #pragma unroll
    for (int j = 0; j < 4; j++) {
      bgf[j] = *(const bf16x8*)&Bgs[(nbase + j * 16 + fl) * 32 + fq * 8];
      buf[j] = *(const bf16x8*)&Bus[(nbase + j * 16 + fl) * 32 + fq * 8];
    }
    #pragma unroll
    for (int i = 0; i < 4; i++)
      #pragma unroll
      for (int j = 0; j < 4; j++) {
        accg[i][j] = __builtin_amdgcn_mfma_f32_16x16x32_bf16(af[i], bgf[j], accg[i][j], 0, 0, 0);
        accu[i][j] = __builtin_amdgcn_mfma_f32_16x16x32_bf16(af[i], buf[j], accu[i][j], 0, 0, 0);
      }
    __syncthreads();
  }
  #pragma unroll
  for (int i = 0; i < 4; i++)
    #pragma unroll
    for (int j = 0; j < 4; j++)
      #pragma unroll
      for (int r = 0; r < 4; r++) {
        int lr = mbase + i * 16 + fq * 4 + r;
        if (r0 + lr < cnt) {
          float g = accg[i][j][r], u = accu[i][j][r];
          float s = g / (1.f + __expf(-g));
          int col = n0 + nbase + j * 16 + fl;
          hb[(size_t)(hoff + r0 + lr) * HM + col] = (bf16)(s * u);
        }
      }
}

// ---------------- GEMM2: y = h @ Wd ----------------
// BM=128 BN=256 BK=32; 4 waves (2M x 2N), each 64x128. Halves A-panel refetch vs BN=128.
__global__ __launch_bounds__(256, 2) void gemm2_kernel(
    const bf16* __restrict__ hb, const bf16* __restrict__ wdT, const bf16* __restrict__ swdT,
    const int* __restrict__ segs, bf16* __restrict__ yb, int e_fixed, int wcompact,
    int hcompact) {
  const int e = (e_fixed >= 0) ? e_fixed : (int)blockIdx.z;
  const int off = segs[e], cnt = segs[8 + e];
  const int hoff = hcompact ? 0 : off;
  const int r0 = blockIdx.y * 128;
  if (r0 >= cnt) return;
  const int n0 = blockIdx.x * 256;
  const size_t estride = wcompact ? 0 : (size_t)e * WEXP_ELEMS;
  const bf16* bd = (e < NE) ? wdT + estride : swdT;

  __shared__ __align__(16) bf16 As[128 * 32];
  __shared__ __align__(16) bf16 Bs[256 * 32];

  const int tid = threadIdx.x, wave = tid >> 6, lane = tid & 63;
  int lr0 = wave * 16 + (lane >> 2);
  int i0 = min(r0 + lr0, cnt - 1);
  int i1 = min(r0 + lr0 + 64, cnt - 1);
  const bf16* agp0 = hb + (size_t)(hoff + i0) * HM + (lane & 3) * 8;
  const bf16* agp1 = hb + (size_t)(hoff + i1) * HM + (lane & 3) * 8;
  const bf16* bgp0 = bd + (size_t)(n0 + lr0) * HM + (lane & 3) * 8;
  bf16* As_w0 = &As[wave * 512];
  bf16* As_w1 = &As[(4 + wave) * 512];
  bf16* Bs_w0 = &Bs[wave * 512];            // rows wave*16 + {0,64,128,192}
  bf16* Bs_w1 = &Bs[wave * 512 + 2048];
  bf16* Bs_w2 = &Bs[wave * 512 + 4096];
  bf16* Bs_w3 = &Bs[wave * 512 + 6144];

  const int wr = wave & 1, wc = wave >> 1;
  const int mbase = wr * 64, nbase = wc * 128;
  const int fl = lane & 15, fq = lane >> 4;
  f32x4 acc[4][8] = {};

  for (int k0 = 0; k0 < HM; k0 += 32) {
    gload_lds16(agp0 + k0, As_w0);
    gload_lds16(agp1 + k0, As_w1);
    gload_lds16(bgp0 + k0, Bs_w0);
    gload_lds16(bgp0 + (size_t)64 * HM + k0, Bs_w1);
    gload_lds16(bgp0 + (size_t)128 * HM + k0, Bs_w2);
    gload_lds16(bgp0 + (size_t)192 * HM + k0, Bs_w3);
    __syncthreads();
    bf16x8 af[4], bfv[8];
    #pragma unroll
    for (int i = 0; i < 4; i++)
      af[i] = *(const bf16x8*)&As[(mbase + i * 16 + fl) * 32 + fq * 8];
    #pragma unroll
    for (int j = 0; j < 8; j++)
      bfv[j] = *(const bf16x8*)&Bs[(nbase + j * 16 + fl) * 32 + fq * 8];
    #pragma unroll
    for (int i = 0; i < 4; i++)
      #pragma unroll
      for (int j = 0; j < 8; j++)
        acc[i][j] = __builtin_amdgcn_mfma_f32_16x16x32_bf16(af[i], bfv[j], acc[i][j], 0, 0, 0);
    __syncthreads();
  }
  #pragma unroll
  for (int i = 0; i < 4; i++)
    #pragma unroll
    for (int j = 0; j < 8; j++)
      #pragma unroll
      for (int r = 0; r < 4; r++) {
        int lr = mbase + i * 16 + fq * 4 + r;
        if (r0 + lr < cnt) {
          int col = n0 + nbase + j * 16 + fl;
          yb[(size_t)(off + r0 + lr) * DM + col] = (bf16)acc[i][j][r];
        }
      }
}

// ---------------- combine: out = w0*y[r0] + w1*y[r1] + y[shared] ----------------
__global__ __launch_bounds__(256) void combine_kernel(
    const bf16* __restrict__ yb, const int* __restrict__ row_of,
    const float* __restrict__ t_w, float* __restrict__ out) {
  int t = blockIdx.x;
  int d = threadIdx.x * 4;
  int r0 = row_of[t * 2], r1 = row_of[t * 2 + 1];
  float w0 = t_w[t * 2], w1 = t_w[t * 2 + 1];
  bf16x4 a = *(const bf16x4*)&yb[(size_t)r0 * DM + d];
  bf16x4 b = *(const bf16x4*)&yb[(size_t)r1 * DM + d];
  bf16x4 c = *(const bf16x4*)&yb[(size_t)(ROWS_R + t) * DM + d];
  float4 o;
  o.x = w0 * (float)a[0] + w1 * (float)b[0] + (float)c[0];
  o.y = w0 * (float)a[1] + w1 * (float)b[1] + (float)c[1];
  o.z = w0 * (float)a[2] + w1 * (float)b[2] + (float)c[2];
  o.w = w0 * (float)a[3] + w1 * (float)b[3] + (float)c[3];
  *(float4*)&out[(size_t)t * DM + d] = o;
}

extern "C" void kernel_launch(void* const* d_in, const int* in_sizes, int n_in,
                              void* d_out, int out_size, void* d_ws, size_t ws_size,
                              hipStream_t stream) {
  const float* x        = (const float*)d_in[0];
  const float* router_w = (const float*)d_in[1];
  const float* w_gate   = (const float*)d_in[2];
  const float* w_up     = (const float*)d_in[3];
  const float* w_down   = (const float*)d_in[4];
  const float* sw_gate  = (const float*)d_in[5];
  const float* sw_up    = (const float*)d_in[6];
  const float* sw_down  = (const float*)d_in[7];
  float* out = (float*)d_out;

  const size_t WB = WEXP_ELEMS * 2;              // bytes per expert weight matrix (bf16)
  const size_t MISC = (size_t)2 << 20;
  const size_t NEED_T1  = (size_t)NTOK * DM * 2 + 21 * WB + 3 * WB +
                          (size_t)ROWS_T * HM * 2 + (size_t)ROWS_T * DM * 2 + MISC;
  const size_t NEED_T14 = (size_t)NTOK * DM * 2 + 21 * WB + 3 * WB +
                          (size_t)ROWS_R * HM * 2 + (size_t)ROWS_T * DM * 2 + MISC;
  const size_t NEED_T15 = (size_t)NTOK * DM * 2 + 2 * WB + 8 * WB +
                          (size_t)ROWS_R * HM * 2 + (size_t)ROWS_T * DM * 2 + MISC;
  const int tier = (ws_size >= NEED_T1 + (16 << 20))  ? 1
                 : (ws_size >= NEED_T14 + (8 << 20))  ? 14
                 : (ws_size >= NEED_T15 + (8 << 20))  ? 15 : 2;

  char* p = (char*)d_ws;
  auto alloc = [&](size_t bytes) { char* r = p; p += (bytes + 255) & ~(size_t)255; return r; };

  bf16* xb = (bf16*)alloc((size_t)NTOK * DM * 2);
  bf16 *wgT, *wuT, *wdT, *swgT, *swuT, *swdT, *hb, *yb;
  if (tier == 1 || tier == 14) {
    wgT  = (bf16*)alloc(7 * WB);
    wuT  = (bf16*)alloc(7 * WB);
    wdT  = (bf16*)alloc(7 * WB);
    swgT = (bf16*)alloc(WB);
    swuT = (bf16*)alloc(WB);
    swdT = (bf16*)alloc(WB);
    hb   = (bf16*)alloc((tier == 1 ? (size_t)ROWS_T : (size_t)ROWS_R) * HM * 2);
  } else if (tier == 15) {
    wgT  = (bf16*)alloc(WB);         // per-expert gate/up slots (also used for shared)
    wuT  = (bf16*)alloc(WB);
    wdT  = (bf16*)alloc(7 * WB);     // ALL routed down-weights resident
    swdT = (bf16*)alloc(WB);
    swgT = wgT; swuT = wuT;
    hb   = (bf16*)alloc((size_t)ROWS_R * HM * 2);   // all routed rows (shared uses prefix)
  } else {
    wgT  = (bf16*)alloc(WB);         // single-expert slots, reused
    wuT  = (bf16*)alloc(WB);
    wdT  = (bf16*)alloc(WB);
    swgT = wgT; swuT = wuT; swdT = wdT;
    hb   = (bf16*)alloc((size_t)NTOK * HM * 2);     // one expert (worst case all tokens)
  }
  yb = (bf16*)alloc((size_t)ROWS_T * DM * 2);
  int* cursor     = (int*)alloc(8 * 4);
  int* segs       = (int*)alloc(16 * 4);
  int* t_idx      = (int*)alloc((size_t)NTOK * 2 * 4);
  int* row_of     = (int*)alloc((size_t)NTOK * 2 * 4);
  int* tok_of_row = (int*)alloc((size_t)ROWS_T * 4);
  float* t_w      = (float*)alloc((size_t)NTOK * 2 * 4);
  if ((size_t)(p - (char*)d_ws) > ws_size) {
    fprintf(stderr, "MoE kernel: ws too small: need %zu have %zu (tier=%d)\n",
            (size_t)(p - (char*)d_ws), ws_size, tier);
    return;  // refuse to launch OOB — fails validation instead of crashing
  }

  hipMemsetAsync(cursor, 0, 8 * 4, stream);

  cvt_bf16_kernel<<<(NTOK * DM) / 1024, 256, 0, stream>>>(x, xb, NTOK * DM);
  router_kernel<<<NTOK / 4, 256, 0, stream>>>(x, router_w, t_idx, t_w);
  hist_kernel<<<1, 1024, 0, stream>>>(t_idx, segs);
  fill_kernel<<<NTOK / 256, 256, 0, stream>>>(t_idx, cursor, segs, tok_of_row, row_of);

  const dim3 tb(32, 8);
  const size_t WE = WEXP_ELEMS;

  if (tier == 1) {
    transpose_cvt_kernel<<<dim3(HM / 32, DM / 32, NE), tb, 0, stream>>>(w_gate, wgT, DM, HM);
    transpose_cvt_kernel<<<dim3(HM / 32, DM / 32, NE), tb, 0, stream>>>(w_up, wuT, DM, HM);
    transpose_cvt_wd<<<dim3(DM / 32, HM / 32, 8), tb, 0, stream>>>(w_down, sw_down, wdT, swdT);
    transpose_cvt_pair<<<dim3(HM / 32, DM / 32, 2), tb, 0, stream>>>(
        sw_gate, sw_up, swgT, swuT, DM, HM);
    gemm1_kernel<<<dim3(HM / 128, 64, 8), 256, 0, stream>>>(
        xb, wgT, wuT, swgT, swuT, segs, tok_of_row, hb, -1, 0, 0);
    gemm2_kernel<<<dim3(DM / 256, 64, 8), 256, 0, stream>>>(
        hb, wdT, swdT, segs, yb, -1, 0, 0);
  } else if (tier == 14) {
    // ---- tier-1.4: all weights transposed up front; shared pass uses hb prefix,
    //      then ONE batched gemm1 + ONE batched gemm2 over all routed experts. ----
    transpose_cvt_kernel<<<dim3(HM / 32, DM / 32, NE), tb, 0, stream>>>(w_gate, wgT, DM, HM);
    transpose_cvt_kernel<<<dim3(HM / 32, DM / 32, NE), tb, 0, stream>>>(w_up, wuT, DM, HM);
    transpose_cvt_wd<<<dim3(DM / 32, HM / 32, 8), tb, 0, stream>>>(w_down, sw_down, wdT, swdT);
    transpose_cvt_pair<<<dim3(HM / 32, DM / 32, 2), tb, 0, stream>>>(
        sw_gate, sw_up, swgT, swuT, DM, HM);
    gemm1_kernel<<<dim3(HM / 128, 64, 1), 256, 0, stream>>>(
        xb, wgT, wuT, swgT, swuT, segs, tok_of_row, hb, 7, 0, 1);
    gemm2_kernel<<<dim3(DM / 256, 64, 1), 256, 0, stream>>>(
        hb, wdT, swdT, segs, yb, 7, 0, 1);
    gemm1_kernel<<<dim3(HM / 128, 64, 7), 256, 0, stream>>>(
        xb, wgT, wuT, swgT, swuT, segs, tok_of_row, hb, -1, 0, 0);
    gemm2_kernel<<<dim3(DM / 256, 64, 7), 256, 0, stream>>>(
        hb, wdT, swdT, segs, yb, -1, 0, 0);
  } else if (tier == 15) {
    // ---- tier-1.5: shared first (compact hb prefix), then routed experts into full hb,
    //      then ONE batched gemm2 over all routed experts. ----
    transpose_cvt_pair<<<dim3(HM / 32, DM / 32, 2), tb, 0, stream>>>(
        sw_gate, sw_up, wgT, wuT, DM, HM);
    gemm1_kernel<<<dim3(HM / 128, 64, 1), 256, 0, stream>>>(
        xb, wgT, wuT, wgT, wuT, segs, tok_of_row, hb, 7, 1, 1);
    transpose_cvt_wd<<<dim3(DM / 32, HM / 32, 8), tb, 0, stream>>>(
        w_down, sw_down, wdT, swdT);
    gemm2_kernel<<<dim3(DM / 256, 64, 1), 256, 0, stream>>>(
        hb, wdT, swdT, segs, yb, 7, 1, 1);
    for (int e = 0; e < NE; e++) {
      transpose_cvt_pair<<<dim3(HM / 32, DM / 32, 2), tb, 0, stream>>>(
          w_gate + (size_t)e * WE, w_up + (size_t)e * WE, wgT, wuT, DM, HM);
      gemm1_kernel<<<dim3(HM / 128, 64, 1), 256, 0, stream>>>(
          xb, wgT, wuT, wgT, wuT, segs, tok_of_row, hb, e, 1, 0);
    }
    gemm2_kernel<<<dim3(DM / 256, 64, 7), 256, 0, stream>>>(
        hb, wdT, swdT, segs, yb, -1, 0, 0);
  } else {
    // ---- tier-2: per-expert slot reuse, fused triple transposes ----
    transpose_cvt3<<<dim3(4096, 1, 3), tb, 0, stream>>>(sw_gate, sw_up, sw_down,
                                                        wgT, wuT, wdT);
    gemm1_kernel<<<dim3(HM / 128, 64, 1), 256, 0, stream>>>(
        xb, wgT, wuT, wgT, wuT, segs, tok_of_row, hb, 7, 1, 1);
    gemm2_kernel<<<dim3(DM / 256, 64, 1), 256, 0, stream>>>(
        hb, wdT, swdT, segs, yb, 7, 1, 1);
    for (int e = 0; e < NE; e++) {
      transpose_cvt3<<<dim3(4096, 1, 3), tb, 0, stream>>>(
          w_gate + (size_t)e * WE, w_up + (size_t)e * WE, w_down + (size_t)e * WE,
          wgT, wuT, wdT);
      gemm1_kernel<<<dim3(HM / 128, 64, 1), 256, 0, stream>>>(
          xb, wgT, wuT, wgT, wuT, segs, tok_of_row, hb, e, 1, 1);
      gemm2_kernel<<<dim3(DM / 256, 64, 1), 256, 0, stream>>>(
          hb, wdT, swdT, segs, yb, e, 1, 1);
    }
  }
  combine_kernel<<<NTOK, 256, 0, stream>>>(yb, row_of, t_w, out);
}

// Round 6
// 1323.151 us; speedup vs baseline: 1.4317x; 1.0227x over previous
//
#include <hip/hip_runtime.h>
#include <cstdint>
#include <cstdio>

#define DM 1024
#define HM 4096
#define NE 7
#define NTOK 8192
#define ROWS_R 16384   // 2*NTOK routed rows
#define ROWS_T 24576   // + NTOK shared rows
#define WEXP_ELEMS ((size_t)HM * DM)

#define TT_PER_MAT 4096                      // (DM/32)*(HM/32) tiles per matrix
#define NMAT 24                              // 7 gate + 7 up + 7 down + 3 shared
#define PREP_TRANS (NMAT * TT_PER_MAT)       // 98304
#define PREP_CVT ((NTOK * DM) / 1024)        // 8192
#define PREP_ROUTER (NTOK / 4)               // 2048
#define PREP_TOTAL (PREP_TRANS + PREP_CVT + PREP_ROUTER)

typedef __bf16 bf16;
typedef __bf16 bf16x8 __attribute__((ext_vector_type(8)));
typedef __bf16 bf16x4 __attribute__((ext_vector_type(4)));
typedef float f32x4 __attribute__((ext_vector_type(4)));
typedef unsigned int u32;

__device__ __forceinline__ void gload_lds16(const bf16* g, bf16* l) {
  __builtin_amdgcn_global_load_lds((const __attribute__((address_space(1))) u32*)g,
                                   (__attribute__((address_space(3))) u32*)l, 16, 0, 0);
}

// ---------------- shared transpose tile body ----------------
__device__ __forceinline__ void transpose_tile(const float* __restrict__ ib,
                                               bf16* __restrict__ ob,
                                               int R, int C, int bx, int by,
                                               int tx, int ty) {
  __shared__ float tile[32][33];
  int c0 = bx * 32, r0 = by * 32;
  #pragma unroll
  for (int i = 0; i < 32; i += 8)
    tile[ty + i][tx] = ib[(size_t)(r0 + ty + i) * C + c0 + tx];
  __syncthreads();
  #pragma unroll
  for (int i = 0; i < 32; i += 8)
    ob[(size_t)(c0 + ty + i) * R + r0 + tx] = (bf16)tile[tx][ty + i];
}

// ---------------- router body (no atomics) ----------------
__device__ __forceinline__ void router_body(const float* __restrict__ x,
                                            const float* __restrict__ rw,
                                            int* __restrict__ t_idx,
                                            float* __restrict__ t_w,
                                            int t, int lane) {
  float acc[NE];
  #pragma unroll
  for (int e = 0; e < NE; e++) acc[e] = 0.f;
  const float* xr = x + (size_t)t * DM;
  for (int i = lane; i < DM; i += 64) {
    float xv = xr[i];
    #pragma unroll
    for (int e = 0; e < NE; e++) acc[e] += xv * rw[e * DM + i];
  }
  #pragma unroll
  for (int e = 0; e < NE; e++) {
    float v = acc[e];
    #pragma unroll
    for (int s = 32; s > 0; s >>= 1) v += __shfl_xor(v, s, 64);
    acc[e] = v;
  }
  if (lane == 0) {
    int b0 = 0; float v0 = acc[0];
    #pragma unroll
    for (int e = 1; e < NE; e++) if (acc[e] > v0) { v0 = acc[e]; b0 = e; }
    int b1 = -1; float v1 = -3.0e38f;
    #pragma unroll
    for (int e = 0; e < NE; e++) if (e != b0 && acc[e] > v1) { v1 = acc[e]; b1 = e; }
    float p0 = 1.f / (1.f + __expf(v1 - v0));  // softmax over top-2 (v0 >= v1)
    t_idx[t * 2] = b0; t_idx[t * 2 + 1] = b1;
    t_w[t * 2] = p0;  t_w[t * 2 + 1] = 1.f - p0;
  }
}

// ---------------- mega-prep: all 24 transposes + x-cvt + router in ONE launch ----------------
__global__ __launch_bounds__(256) void prep_kernel(
    const float* __restrict__ x, const float* __restrict__ rw,
    const float* __restrict__ w_gate, const float* __restrict__ w_up,
    const float* __restrict__ w_down, const float* __restrict__ sw_gate,
    const float* __restrict__ sw_up, const float* __restrict__ sw_down,
    bf16* __restrict__ xb, bf16* __restrict__ wgT, bf16* __restrict__ wuT,
    bf16* __restrict__ wdT, int* __restrict__ t_idx, float* __restrict__ t_w) {
  const int bid = blockIdx.x, tid = threadIdx.x;
  if (bid < PREP_TRANS) {
    int mat = bid / TT_PER_MAT, tile = bid % TT_PER_MAT;
    const float* src; bf16* dst; int R, C;
    if (mat < 7)       { src = w_gate + (size_t)mat * WEXP_ELEMS;
                         dst = wgT + (size_t)mat * WEXP_ELEMS;        R = DM; C = HM; }
    else if (mat < 14) { src = w_up + (size_t)(mat - 7) * WEXP_ELEMS;
                         dst = wuT + (size_t)(mat - 7) * WEXP_ELEMS;  R = DM; C = HM; }
    else if (mat < 21) { src = w_down + (size_t)(mat - 14) * WEXP_ELEMS;
                         dst = wdT + (size_t)(mat - 14) * WEXP_ELEMS; R = HM; C = DM; }
    else if (mat == 21){ src = sw_gate; dst = wgT + (size_t)7 * WEXP_ELEMS; R = DM; C = HM; }
    else if (mat == 22){ src = sw_up;   dst = wuT + (size_t)7 * WEXP_ELEMS; R = DM; C = HM; }
    else               { src = sw_down; dst = wdT + (size_t)7 * WEXP_ELEMS; R = HM; C = DM; }
    int nbx = C / 32;
    transpose_tile(src, dst, R, C, tile % nbx, tile / nbx, tid & 31, tid >> 5);
  } else if (bid < PREP_TRANS + PREP_CVT) {
    int i = ((bid - PREP_TRANS) * 256 + tid) * 4;
    float4 v = *(const float4*)(x + i);
    bf16x4 o; o[0] = (bf16)v.x; o[1] = (bf16)v.y; o[2] = (bf16)v.z; o[3] = (bf16)v.w;
    *(bf16x4*)(xb + i) = o;
  } else {
    int rb = bid - PREP_TRANS - PREP_CVT;
    router_body(x, rw, t_idx, t_w, rb * 4 + (tid >> 6), tid & 63);
  }
}

// ---------------- standalone kernels (fallback tiers) ----------------
__global__ void cvt_bf16_kernel(const float* __restrict__ in, bf16* __restrict__ out, int n) {
  int i = (blockIdx.x * 256 + threadIdx.x) * 4;
  if (i >= n) return;
  float4 v = *(const float4*)(in + i);
  bf16x4 o; o[0] = (bf16)v.x; o[1] = (bf16)v.y; o[2] = (bf16)v.z; o[3] = (bf16)v.w;
  *(bf16x4*)(out + i) = o;
}

__global__ __launch_bounds__(256) void router_kernel(
    const float* __restrict__ x, const float* __restrict__ rw,
    int* __restrict__ t_idx, float* __restrict__ t_w) {
  router_body(x, rw, t_idx, t_w, blockIdx.x * 4 + (threadIdx.x >> 6), threadIdx.x & 63);
}

__global__ void transpose_cvt_pair(const float* __restrict__ s0, const float* __restrict__ s1,
                                   bf16* __restrict__ d0, bf16* __restrict__ d1,
                                   int R, int C) {
  const float* ib = blockIdx.z ? s1 : s0;
  bf16* ob = blockIdx.z ? d1 : d0;
  transpose_tile(ib, ob, R, C, blockIdx.x, blockIdx.y, threadIdx.x, threadIdx.y);
}

__global__ void transpose_cvt_wd(const float* __restrict__ wd, const float* __restrict__ swd,
                                 bf16* __restrict__ wdT, bf16* __restrict__ swdT) {
  int z = blockIdx.z;
  const float* ib = (z < NE) ? wd + (size_t)z * WEXP_ELEMS : swd;
  bf16* ob = (z < NE) ? wdT + (size_t)z * WEXP_ELEMS : swdT;
  transpose_tile(ib, ob, HM, DM, blockIdx.x, blockIdx.y, threadIdx.x, threadIdx.y);
}

__global__ void transpose_cvt3(const float* __restrict__ g, const float* __restrict__ u,
                               const float* __restrict__ d,
                               bf16* __restrict__ og, bf16* __restrict__ ou,
                               bf16* __restrict__ od) {
  int z = blockIdx.z;
  int R = (z == 2) ? HM : DM, C = (z == 2) ? DM : HM;
  int nbx = C / 32;
  int bid = blockIdx.x;
  const float* ib = (z == 0) ? g : ((z == 1) ? u : d);
  bf16* ob = (z == 0) ? og : ((z == 1) ? ou : od);
  transpose_tile(ib, ob, R, C, bid % nbx, bid / nbx, threadIdx.x, threadIdx.y);
}

// ---------------- histogram + prefix ----------------
__global__ __launch_bounds__(1024) void hist_kernel(const int* __restrict__ t_idx,
                                                    int* __restrict__ segs) {
  const int tid = threadIdx.x, wave = tid >> 6, lane = tid & 63;
  int c[NE];
  #pragma unroll
  for (int e = 0; e < NE; e++) c[e] = 0;
  for (int i = tid; i < NTOK * 2; i += 1024) {
    int e = t_idx[i];
    #pragma unroll
    for (int k = 0; k < NE; k++) c[k] += (e == k) ? 1 : 0;
  }
  __shared__ int ws[16][8];
  #pragma unroll
  for (int k = 0; k < NE; k++) {
    int v = c[k];
    #pragma unroll
    for (int s = 32; s > 0; s >>= 1) v += __shfl_xor(v, s, 64);
    if (lane == 0) ws[wave][k] = v;
  }
  __syncthreads();
  if (tid == 0) {
    int o = 0;
    for (int e = 0; e < NE; e++) {
      int cnt = 0;
      for (int w = 0; w < 16; w++) cnt += ws[w][e];
      segs[e] = o; segs[8 + e] = cnt; o += cnt;
    }
    segs[7] = ROWS_R;   // shared expert segment
    segs[15] = NTOK;
  }
}

// ---------------- fill per-expert row lists ----------------
__global__ __launch_bounds__(256) void fill_kernel(
    const int* __restrict__ t_idx, int* __restrict__ cursor,
    const int* __restrict__ segs, int* __restrict__ tok_of_row,
    int* __restrict__ row_of) {
  __shared__ int wcnt[2][4][8];
  __shared__ int wbase[2][4][8];
  __shared__ int bbase[8];
  const int tid = threadIdx.x, wave = tid >> 6, lane = tid & 63;
  const int t = blockIdx.x * 256 + tid;
  const int e0 = t_idx[t * 2], e1 = t_idx[t * 2 + 1];
  const unsigned long long lt = (1ull << lane) - 1ull;
  int rank0 = 0, rank1 = 0;
  #pragma unroll
  for (int e = 0; e < NE; e++) {
    unsigned long long m0 = __ballot(e0 == e);
    unsigned long long m1 = __ballot(e1 == e);
    if (e0 == e) rank0 = __popcll(m0 & lt);
    if (e1 == e) rank1 = __popcll(m1 & lt);
    if (lane == 0) { wcnt[0][wave][e] = __popcll(m0); wcnt[1][wave][e] = __popcll(m1); }
  }
  __syncthreads();
  if (tid < NE) {
    int e = tid, run = 0;
    #pragma unroll
    for (int s = 0; s < 2; s++)
      #pragma unroll
      for (int w = 0; w < 4; w++) { wbase[s][w][e] = run; run += wcnt[s][w][e]; }
    bbase[e] = segs[e] + atomicAdd(&cursor[e], run);
  }
  __syncthreads();
  int r0 = bbase[e0] + wbase[0][wave][e0] + rank0;
  int r1 = bbase[e1] + wbase[1][wave][e1] + rank1;
  tok_of_row[r0] = t;  row_of[t * 2] = r0;
  tok_of_row[r1] = t;  row_of[t * 2 + 1] = r1;
  tok_of_row[ROWS_R + t] = t;
}

// ---------------- GEMM1: h = silu(x@Wg) * (x@Wu), gathered rows ----------------
// BM=128 BN=64 BK=32; 4 waves, each 64rows x 32cols per matrix; two B matrices fused.
__global__ __launch_bounds__(256, 2) void gemm1_kernel(
    const bf16* __restrict__ xb, const bf16* __restrict__ wgT, const bf16* __restrict__ wuT,
    const bf16* __restrict__ swgT, const bf16* __restrict__ swuT,
    const int* __restrict__ segs, const int* __restrict__ tok_of_row,
    bf16* __restrict__ hb, int e_fixed, int wcompact, int hcompact) {
  const int e = (e_fixed >= 0) ? e_fixed : (int)blockIdx.z;
  const int off = segs[e], cnt = segs[8 + e];
  const int hoff = hcompact ? 0 : off;
  const int r0 = blockIdx.y * 128;
  if (r0 >= cnt) return;
  const int n0 = blockIdx.x * 64;
  const size_t estride = wcompact ? 0 : (size_t)e * WEXP_ELEMS;
  const bf16* bg = (e < NE) ? wgT + estride : swgT;
  const bf16* bu = (e < NE) ? wuT + estride : swuT;

  __shared__ __align__(16) bf16 As[128 * 32];
  __shared__ __align__(16) bf16 Bgs[64 * 32];
  __shared__ __align__(16) bf16 Bus[64 * 32];

  const int tid = threadIdx.x, wave = tid >> 6, lane = tid & 63;
  int lr0 = wave * 16 + (lane >> 2);
  int lr1 = lr0 + 64;
  int i0 = min(r0 + lr0, cnt - 1);
  int i1 = min(r0 + lr1, cnt - 1);
  const bf16* agp0 = xb + (size_t)tok_of_row[off + i0] * DM + (lane & 3) * 8;
  const bf16* agp1 = xb + (size_t)tok_of_row[off + i1] * DM + (lane & 3) * 8;
  const bf16* bgp = bg + (size_t)(n0 + lr0) * DM + (lane & 3) * 8;
  const bf16* bup = bu + (size_t)(n0 + lr0) * DM + (lane & 3) * 8;
  bf16* As_w0 = &As[wave * 512];
  bf16* As_w1 = &As[(4 + wave) * 512];
  bf16* Bgs_w = &Bgs[wave * 512];
  bf16* Bus_w = &Bus[wave * 512];

  const int wr = wave & 1, wc = wave >> 1;
  const int mbase = wr * 64, nbase = wc * 32;
  const int fl = lane & 15, fq = lane >> 4;
  f32x4 accg[4][2] = {}; f32x4 accu[4][2] = {};

  for (int k0 = 0; k0 < DM; k0 += 32) {
    gload_lds16(agp0 + k0, As_w0);
    gload_lds16(agp1 + k0, As_w1);
    gload_lds16(bgp + k0, Bgs_w);
    gload_lds16(bup + k0, Bus_w);
    __syncthreads();
    bf16x8 af[4], bgf[2], buf[2];
    #pragma unroll
    for (int i = 0; i < 4; i++)
      af[i] = *(const bf16x8*)&As[(mbase + i * 16 + fl) * 32 + fq * 8];
    #pragma unroll
    for (int j = 0; j < 2; j++) {
      bgf[j] = *(const bf16x8*)&Bgs[(nbase + j * 16 + fl) * 32 + fq * 8];
      buf[j] = *(const bf16x8*)&Bus[(nbase + j * 16 + fl) * 32 + fq * 8];
    }
    #pragma unroll
    for (int i = 0; i < 4; i++)
      #pragma unroll
      for (int j = 0; j < 2; j++) {
        accg[i][j] = __builtin_amdgcn_mfma_f32_16x16x32_bf16(af[i], bgf[j], accg[i][j], 0, 0, 0);
        accu[i][j] = __builtin_amdgcn_mfma_f32_16x16x32_bf16(af[i], buf[j], accu[i][j], 0, 0, 0);
      }
    __syncthreads();
  }
  #pragma unroll
  for (int i = 0; i < 4; i++)
    #pragma unroll
    for (int j = 0; j < 2; j++)
      #pragma unroll
      for (int r = 0; r < 4; r++) {
        int lr = mbase + i * 16 + fq * 4 + r;
        if (r0 + lr < cnt) {
          float g = accg[i][j][r], u = accu[i][j][r];
          float s = g / (1.f + __expf(-g));
          int col = n0 + nbase + j * 16 + fl;
          hb[(size_t)(hoff + r0 + lr) * HM + col] = (bf16)(s * u);
        }
      }
}

// ---------------- GEMM2: y = h @ Wd ----------------
// BM=128 BN=256 BK=32; 4 waves (2M x 2N), each 64x128.
__global__ __launch_bounds__(256, 2) void gemm2_kernel(
    const bf16* __restrict__ hb, const bf16* __restrict__ wdT, const bf16* __restrict__ swdT,
    const int* __restrict__ segs, bf16* __restrict__ yb, int e_fixed, int wcompact,
    int hcompact) {
  const int e = (e_fixed >= 0) ? e_fixed : (int)blockIdx.z;
  const int off = segs[e], cnt = segs[8 + e];
  const int hoff = hcompact ? 0 : off;
  const int r0 = blockIdx.y * 128;
  if (r0 >= cnt) return;
  const int n0 = blockIdx.x * 256;
  const size_t estride = wcompact ? 0 : (size_t)e * WEXP_ELEMS;
  const bf16* bd = (e < NE) ? wdT + estride : swdT;

  __shared__ __align__(16) bf16 As[128 * 32];
  __shared__ __align__(16) bf16 Bs[256 * 32];

  const int tid = threadIdx.x, wave = tid >> 6, lane = tid & 63;
  int lr0 = wave * 16 + (lane >> 2);
  int i0 = min(r0 + lr0, cnt - 1);
  int i1 = min(r0 + lr0 + 64, cnt - 1);
  const bf16* agp0 = hb + (size_t)(hoff + i0) * HM + (lane & 3) * 8;
  const bf16* agp1 = hb + (size_t)(hoff + i1) * HM + (lane & 3) * 8;
  const bf16* bgp0 = bd + (size_t)(n0 + lr0) * HM + (lane & 3) * 8;
  bf16* As_w0 = &As[wave * 512];
  bf16* As_w1 = &As[(4 + wave) * 512];
  bf16* Bs_w0 = &Bs[wave * 512];
  bf16* Bs_w1 = &Bs[wave * 512 + 2048];
  bf16* Bs_w2 = &Bs[wave * 512 + 4096];
  bf16* Bs_w3 = &Bs[wave * 512 + 6144];

  const int wr = wave & 1, wc = wave >> 1;
  const int mbase = wr * 64, nbase = wc * 128;
  const int fl = lane & 15, fq = lane >> 4;
  f32x4 acc[4][8] = {};

  for (int k0 = 0; k0 < HM; k0 += 32) {
    gload_lds16(agp0 + k0, As_w0);
    gload_lds16(agp1 + k0, As_w1);
    gload_lds16(bgp0 + k0, Bs_w0);
    gload_lds16(bgp0 + (size_t)64 * HM + k0, Bs_w1);
    gload_lds16(bgp0 + (size_t)128 * HM + k0, Bs_w2);
    gload_lds16(bgp0 + (size_t)192 * HM + k0, Bs_w3);
    __syncthreads();
    bf16x8 af[4], bfv[8];
    #pragma unroll
    for (int i = 0; i < 4; i++)
      af[i] = *(const bf16x8*)&As[(mbase + i * 16 + fl) * 32 + fq * 8];
    #pragma unroll
    for (int j = 0; j < 8; j++)
      bfv[j] = *(const bf16x8*)&Bs[(nbase + j * 16 + fl) * 32 + fq * 8];
    #pragma unroll
    for (int i = 0; i < 4; i++)
      #pragma unroll
      for (int j = 0; j < 8; j++)
        acc[i][j] = __builtin_amdgcn_mfma_f32_16x16x32_bf16(af[i], bfv[j], acc[i][j], 0, 0, 0);
    __syncthreads();
  }
  #pragma unroll
  for (int i = 0; i < 4; i++)
    #pragma unroll
    for (int j = 0; j < 8; j++)
      #pragma unroll
      for (int r = 0; r < 4; r++) {
        int lr = mbase + i * 16 + fq * 4 + r;
        if (r0 + lr < cnt) {
          int col = n0 + nbase + j * 16 + fl;
          yb[(size_t)(off + r0 + lr) * DM + col] = (bf16)acc[i][j][r];
        }
      }
}

// ---------------- combine: out = w0*y[r0] + w1*y[r1] + y[shared] ----------------
__global__ __launch_bounds__(256) void combine_kernel(
    const bf16* __restrict__ yb, const int* __restrict__ row_of,
    const float* __restrict__ t_w, float* __restrict__ out) {
  int t = blockIdx.x;
  int d = threadIdx.x * 4;
  int r0 = row_of[t * 2], r1 = row_of[t * 2 + 1];
  float w0 = t_w[t * 2], w1 = t_w[t * 2 + 1];
  bf16x4 a = *(const bf16x4*)&yb[(size_t)r0 * DM + d];
  bf16x4 b = *(const bf16x4*)&yb[(size_t)r1 * DM + d];
  bf16x4 c = *(const bf16x4*)&yb[(size_t)(ROWS_R + t) * DM + d];
  float4 o;
  o.x = w0 * (float)a[0] + w1 * (float)b[0] + (float)c[0];
  o.y = w0 * (float)a[1] + w1 * (float)b[1] + (float)c[1];
  o.z = w0 * (float)a[2] + w1 * (float)b[2] + (float)c[2];
  o.w = w0 * (float)a[3] + w1 * (float)b[3] + (float)c[3];
  *(float4*)&out[(size_t)t * DM + d] = o;
}

extern "C" void kernel_launch(void* const* d_in, const int* in_sizes, int n_in,
                              void* d_out, int out_size, void* d_ws, size_t ws_size,
                              hipStream_t stream) {
  const float* x        = (const float*)d_in[0];
  const float* router_w = (const float*)d_in[1];
  const float* w_gate   = (const float*)d_in[2];
  const float* w_up     = (const float*)d_in[3];
  const float* w_down   = (const float*)d_in[4];
  const float* sw_gate  = (const float*)d_in[5];
  const float* sw_up    = (const float*)d_in[6];
  const float* sw_down  = (const float*)d_in[7];
  float* out = (float*)d_out;

  const size_t WB = WEXP_ELEMS * 2;              // bytes per expert weight matrix (bf16)
  const size_t MISC = (size_t)2 << 20;
  // lean tiers: shared weights live in slot 7 of 8-slot arrays (24 WB total)
  const size_t NEED_T1  = (size_t)NTOK * DM * 2 + 24 * WB +
                          (size_t)ROWS_T * HM * 2 + (size_t)ROWS_T * DM * 2 + MISC;
  const size_t NEED_T14 = (size_t)NTOK * DM * 2 + 24 * WB +
                          (size_t)ROWS_R * HM * 2 + (size_t)ROWS_T * DM * 2 + MISC;
  const size_t NEED_T15 = (size_t)NTOK * DM * 2 + 2 * WB + 8 * WB +
                          (size_t)ROWS_R * HM * 2 + (size_t)ROWS_T * DM * 2 + MISC;
  const int tier = (ws_size >= NEED_T1 + (4 << 20))   ? 1
                 : (ws_size >= NEED_T14 + (4 << 20))  ? 14
                 : (ws_size >= NEED_T15 + (4 << 20))  ? 15 : 2;

  char* p = (char*)d_ws;
  auto alloc = [&](size_t bytes) { char* r = p; p += (bytes + 255) & ~(size_t)255; return r; };

  bf16* xb = (bf16*)alloc((size_t)NTOK * DM * 2);
  bf16 *wgT, *wuT, *wdT, *swgT, *swuT, *swdT, *hb, *yb;
  if (tier == 1 || tier == 14) {
    wgT  = (bf16*)alloc(8 * WB);     // slots 0-6 routed, slot 7 shared
    wuT  = (bf16*)alloc(8 * WB);
    wdT  = (bf16*)alloc(8 * WB);
    swgT = wgT + 7 * WEXP_ELEMS;
    swuT = wuT + 7 * WEXP_ELEMS;
    swdT = wdT + 7 * WEXP_ELEMS;
    hb   = (bf16*)alloc((tier == 1 ? (size_t)ROWS_T : (size_t)ROWS_R) * HM * 2);
  } else if (tier == 15) {
    wgT  = (bf16*)alloc(WB);
    wuT  = (bf16*)alloc(WB);
    wdT  = (bf16*)alloc(7 * WB);
    swdT = (bf16*)alloc(WB);
    swgT = wgT; swuT = wuT;
    hb   = (bf16*)alloc((size_t)ROWS_R * HM * 2);
  } else {
    wgT  = (bf16*)alloc(WB);
    wuT  = (bf16*)alloc(WB);
    wdT  = (bf16*)alloc(WB);
    swgT = wgT; swuT = wuT; swdT = wdT;
    hb   = (bf16*)alloc((size_t)NTOK * HM * 2);
  }
  yb = (bf16*)alloc((size_t)ROWS_T * DM * 2);
  int* cursor     = (int*)alloc(8 * 4);
  int* segs       = (int*)alloc(16 * 4);
  int* t_idx      = (int*)alloc((size_t)NTOK * 2 * 4);
  int* row_of     = (int*)alloc((size_t)NTOK * 2 * 4);
  int* tok_of_row = (int*)alloc((size_t)ROWS_T * 4);
  float* t_w      = (float*)alloc((size_t)NTOK * 2 * 4);
  if ((size_t)(p - (char*)d_ws) > ws_size) {
    fprintf(stderr, "MoE kernel: ws too small: need %zu have %zu (tier=%d)\n",
            (size_t)(p - (char*)d_ws), ws_size, tier);
    return;
  }

  hipMemsetAsync(cursor, 0, 8 * 4, stream);

  const dim3 tb(32, 8);
  const size_t WE = WEXP_ELEMS;

  if (tier == 1 || tier == 14) {
    prep_kernel<<<PREP_TOTAL, 256, 0, stream>>>(
        x, router_w, w_gate, w_up, w_down, sw_gate, sw_up, sw_down,
        xb, wgT, wuT, wdT, t_idx, t_w);
  } else {
    cvt_bf16_kernel<<<(NTOK * DM) / 1024, 256, 0, stream>>>(x, xb, NTOK * DM);
    router_kernel<<<NTOK / 4, 256, 0, stream>>>(x, router_w, t_idx, t_w);
  }
  hist_kernel<<<1, 1024, 0, stream>>>(t_idx, segs);
  fill_kernel<<<NTOK / 256, 256, 0, stream>>>(t_idx, cursor, segs, tok_of_row, row_of);

  if (tier == 1) {
    // single z=8 launches: routed experts 0-6 + shared (e=7 uses swgT/swuT/swdT = slot 7)
    gemm1_kernel<<<dim3(HM / 64, 64, 8), 256, 0, stream>>>(
        xb, wgT, wuT, swgT, swuT, segs, tok_of_row, hb, -1, 0, 0);
    gemm2_kernel<<<dim3(DM / 256, 64, 8), 256, 0, stream>>>(
        hb, wdT, swdT, segs, yb, -1, 0, 0);
  } else if (tier == 14) {
    // shared first (hb prefix reuse), then batched routed
    gemm1_kernel<<<dim3(HM / 64, 64, 1), 256, 0, stream>>>(
        xb, wgT, wuT, swgT, swuT, segs, tok_of_row, hb, 7, 0, 1);
    gemm2_kernel<<<dim3(DM / 256, 64, 1), 256, 0, stream>>>(
        hb, wdT, swdT, segs, yb, 7, 0, 1);
    gemm1_kernel<<<dim3(HM / 64, 64, 7), 256, 0, stream>>>(
        xb, wgT, wuT, swgT, swuT, segs, tok_of_row, hb, -1, 0, 0);
    gemm2_kernel<<<dim3(DM / 256, 64, 7), 256, 0, stream>>>(
        hb, wdT, swdT, segs, yb, -1, 0, 0);
  } else if (tier == 15) {
    transpose_cvt_pair<<<dim3(HM / 32, DM / 32, 2), tb, 0, stream>>>(
        sw_gate, sw_up, wgT, wuT, DM, HM);
    gemm1_kernel<<<dim3(HM / 64, 64, 1), 256, 0, stream>>>(
        xb, wgT, wuT, wgT, wuT, segs, tok_of_row, hb, 7, 1, 1);
    transpose_cvt_wd<<<dim3(DM / 32, HM / 32, 8), tb, 0, stream>>>(
        w_down, sw_down, wdT, swdT);
    gemm2_kernel<<<dim3(DM / 256, 64, 1), 256, 0, stream>>>(
        hb, wdT, swdT, segs, yb, 7, 1, 1);
    for (int e = 0; e < NE; e++) {
      transpose_cvt_pair<<<dim3(HM / 32, DM / 32, 2), tb, 0, stream>>>(
          w_gate + (size_t)e * WE, w_up + (size_t)e * WE, wgT, wuT, DM, HM);
      gemm1_kernel<<<dim3(HM / 64, 64, 1), 256, 0, stream>>>(
          xb, wgT, wuT, wgT, wuT, segs, tok_of_row, hb, e, 1, 0);
    }
    gemm2_kernel<<<dim3(DM / 256, 64, 7), 256, 0, stream>>>(
        hb, wdT, swdT, segs, yb, -1, 0, 0);
  } else {
    transpose_cvt3<<<dim3(4096, 1, 3), tb, 0, stream>>>(sw_gate, sw_up, sw_down,
                                                        wgT, wuT, wdT);
    gemm1_kernel<<<dim3(HM / 64, 64, 1), 256, 0, stream>>>(
        xb, wgT, wuT, wgT, wuT, segs, tok_of_row, hb, 7, 1, 1);
    gemm2_kernel<<<dim3(DM / 256, 64, 1), 256, 0, stream>>>(
        hb, wdT, swdT, segs, yb, 7, 1, 1);
    for (int e = 0; e < NE; e++) {
      transpose_cvt3<<<dim3(4096, 1, 3), tb, 0, stream>>>(
          w_gate + (size_t)e * WE, w_up + (size_t)e * WE, w_down + (size_t)e * WE,
          wgT, wuT, wdT);
      gemm1_kernel<<<dim3(HM / 64, 64, 1), 256, 0, stream>>>(
          xb, wgT, wuT, wgT, wuT, segs, tok_of_row, hb, e, 1, 1);
      gemm2_kernel<<<dim3(DM / 256, 64, 1), 256, 0, stream>>>(
          hb, wdT, swdT, segs, yb, e, 1, 1);
    }
  }
  combine_kernel<<<NTOK, 256, 0, stream>>>(yb, row_of, t_w, out);
}